// Round 3
// baseline (957.683 us; speedup 1.0000x reference)
//
#include <hip/hip_runtime.h>
#include <math.h>

#define B_SZ 256
#define N_TOKENS 196
#define DIM 384
#define NH 8
#define QKV_ST 1536      // NH*(2*32+128)
#define HID 1536
#define CTX_ST 1024      // NH*128
#define VT_ST 224        // padded token stride of V^T (14*16), cols 196..223 zeroed

typedef short s16x8_base __attribute__((ext_vector_type(8)));
typedef s16x8_base __attribute__((may_alias)) s16x8;
typedef float f32x4_base __attribute__((ext_vector_type(4)));
typedef f32x4_base __attribute__((may_alias)) f32x4;

__device__ inline unsigned short f2b(float f) {
  union { float f; unsigned int u; } v; v.f = f;
  unsigned int r = (v.u + 0x7FFFu + ((v.u >> 16) & 1u)) >> 16;   // RNE, finite inputs
  return (unsigned short)r;
}

// ---------------- fp32 -> bf16 convert (vectorized, grid-stride) ----------------
__global__ __launch_bounds__(256)
void cvt_f32_bf16(const float* __restrict__ in, unsigned short* __restrict__ out, int n4) {
  int i = blockIdx.x * 256 + threadIdx.x;
  const int stride = gridDim.x * 256;
  for (; i < n4; i += stride) {
    float4 v = ((const float4*)in)[i];
    ushort4 o;
    o.x = f2b(v.x); o.y = f2b(v.y); o.z = f2b(v.z); o.w = f2b(v.w);
    ((ushort4*)out)[i] = o;
  }
}

// ---------------- bf16 MFMA GEMM: C[M][N] = A[M][K] @ B[N][K]^T + bias ----------------
// 128x128 tile, BK=32, 256 threads, wave-tile 64x64 (4x4 of 16x16x32).
// Reg-staged double-buffer prefetch (round-0 known-good structure).
template <int OUT_BF16>
__global__ __launch_bounds__(256)
void gemm_bf16_bt(const unsigned short* __restrict__ A,
                  const unsigned short* __restrict__ Bm,
                  const float* __restrict__ bias,
                  void* __restrict__ C, int M, int N, int K) {
  __shared__ unsigned short As[128][32];
  __shared__ unsigned short Bs[128][32];
  const int tid = threadIdx.x;
  const int lane = tid & 63, wave = tid >> 6;
  const int quad = lane >> 4, l15 = lane & 15;
  const int ntile = N >> 7;
  const int bx = blockIdx.x % ntile, by = blockIdx.x / ntile;
  const int row0 = by << 7, col0 = bx << 7;

  const int srow = tid >> 1, soff = (tid & 1) << 4;   // staging: 32B per thread
  const unsigned short* Ag = A + (size_t)(row0 + srow) * K + soff;
  const unsigned short* Bg = Bm + (size_t)(col0 + srow) * K + soff;

  const int wr = (wave >> 1) << 6, wc = (wave & 1) << 6;

  f32x4 zero = {0.f, 0.f, 0.f, 0.f};
  f32x4 acc[4][4];
#pragma unroll
  for (int i = 0; i < 4; ++i)
#pragma unroll
    for (int j = 0; j < 4; ++j) acc[i][j] = zero;

  s16x8 a0 = *(const s16x8*)(Ag + 0);
  s16x8 a1 = *(const s16x8*)(Ag + 8);
  s16x8 b0 = *(const s16x8*)(Bg + 0);
  s16x8 b1 = *(const s16x8*)(Bg + 8);

  for (int k0 = 0; k0 < K; k0 += 32) {
    __syncthreads();
    *(s16x8*)&As[srow][soff] = a0;
    *(s16x8*)&As[srow][soff + 8] = a1;
    *(s16x8*)&Bs[srow][soff] = b0;
    *(s16x8*)&Bs[srow][soff + 8] = b1;
    __syncthreads();
    if (k0 + 32 < K) {
      a0 = *(const s16x8*)(Ag + k0 + 32);
      a1 = *(const s16x8*)(Ag + k0 + 40);
      b0 = *(const s16x8*)(Bg + k0 + 32);
      b1 = *(const s16x8*)(Bg + k0 + 40);
    }
    s16x8 af[4], bf[4];
#pragma unroll
    for (int i = 0; i < 4; ++i) {
      af[i] = *(const s16x8*)&As[wr + i * 16 + l15][quad * 8];
      bf[i] = *(const s16x8*)&Bs[wc + i * 16 + l15][quad * 8];
    }
#pragma unroll
    for (int i = 0; i < 4; ++i)
#pragma unroll
      for (int j = 0; j < 4; ++j)
        acc[i][j] = __builtin_amdgcn_mfma_f32_16x16x32_bf16(af[i], bf[j], acc[i][j], 0, 0, 0);
  }

#pragma unroll
  for (int j = 0; j < 4; ++j) {
    const int col = col0 + wc + j * 16 + l15;
    const float bj = bias[col];
#pragma unroll
    for (int i = 0; i < 4; ++i) {
      const int rowb = row0 + wr + i * 16 + quad * 4;
#pragma unroll
      for (int r = 0; r < 4; ++r) {
        float v = acc[i][j][r] + bj;
        if (OUT_BF16)
          ((unsigned short*)C)[(size_t)(rowb + r) * N + col] = f2b(v);
        else
          ((float*)C)[(size_t)(rowb + r) * N + col] = v;
      }
    }
  }
}

// ---------------- V -> V^T (per (b,h): [196][128] -> [128][224], zero-padded) ----------------
__global__ __launch_bounds__(256)
void transpose_v(const unsigned short* __restrict__ qkv, unsigned short* __restrict__ vt) {
  __shared__ unsigned short ts[32][36];
  const int id = blockIdx.x;
  const int tile = id % 28;
  const int bh = id / 28;
  const int b = bh >> 3, h = bh & 7;
  const int nt = tile % 7, dt = tile / 7;
  const int n0 = nt * 32, d0 = dt * 32;
  const int t = threadIdx.x;
  {
    const int nl = t >> 3, dq = (t & 7) << 2;
    ushort4 v4; v4.x = 0; v4.y = 0; v4.z = 0; v4.w = 0;
    if (n0 + nl < 196)
      v4 = *(const ushort4*)(qkv + ((size_t)(b * 196 + n0 + nl) * QKV_ST + h * 192 + 64 + d0 + dq));
    ts[dq + 0][nl] = v4.x; ts[dq + 1][nl] = v4.y;
    ts[dq + 2][nl] = v4.z; ts[dq + 3][nl] = v4.w;
  }
  __syncthreads();
  {
    const int dl = t >> 3, nq = (t & 7) << 2;   // n0+nq <= 220 < 224 always
    ushort4 o;
    o.x = ts[dl][nq + 0]; o.y = ts[dl][nq + 1];
    o.z = ts[dl][nq + 2]; o.w = ts[dl][nq + 3];
    *(ushort4*)(vt + ((size_t)(bh * 128 + d0 + dl) * VT_ST + n0 + nq)) = o;
  }
}

// ---------------- Flash MFMA attention: one block per (b,h) ----------------
// Chunk over m (keys), 64 m per chunk. out^T accumulator lives in registers
// (wave owns 32 d-rows, permuted for contiguous stores). Q/K/V^T each read
// from global exactly ONCE per block -> compulsory traffic only.
// S-phase: waves split by m-tile (balanced). Online softmax stats (running
// max/sum per n) combined by a single 208-thread LDS pass per chunk.
#define PST 72            // Pm stride: 144B = 16B-aligned, uniform 8-deep banks

template <int NMT, int NKS>
__device__ __forceinline__ void flash_chunk(
    const int chunk, const unsigned short* __restrict__ qbase,
    const unsigned short* __restrict__ vgw,
    const float* __restrict__ ab_s,
    unsigned short (*__restrict__ Pm)[PST],
    float* __restrict__ rmx, float* __restrict__ rsum, float* __restrict__ scale_s,
    float (*__restrict__ pmax)[208], float (*__restrict__ psum)[208],
    f32x4 (&acc0)[13], f32x4 (&acc1)[13],
    const int tid, const int w, const int quad, const int l15) {
  const float scale = 0.17677669529663687f;
  f32x4 zero = {0.f, 0.f, 0.f, 0.f};
  f32x4 sacc[13];

  // ---- Phase A: S tiles (wave's m-tile x all 13 n-tiles), partial row-max ----
  if (w < NMT) {
    const int mt = chunk * 4 + w;
    const int mm = mt * 16 + l15;
    s16x8 bk = *(const s16x8*)(qbase + (size_t)mm * QKV_ST + 32 + quad * 8);
#pragma unroll
    for (int i = 0; i < 13; ++i) {
      s16x8 aq = *(const s16x8*)(qbase + (size_t)(i * 16 + l15) * QKV_ST + quad * 8);
      sacc[i] = __builtin_amdgcn_mfma_f32_16x16x32_bf16(aq, bk, zero, 0, 0, 0);
    }
    const int mmc = mm < 196 ? mm : 195;
    const int rm = mmc / 14, cm = mmc - rm * 14;
    const bool mok = mm < 196;
#pragma unroll
    for (int i = 0; i < 13; ++i) {
#pragma unroll
      for (int r = 0; r < 4; ++r) {
        const int n = i * 16 + quad * 4 + r;
        const int nn = n < 196 ? n : 195;
        const int rn = nn / 14, cn = nn - rn * 14;
        int dr = rn - rm; dr = dr < 0 ? -dr : dr;
        int dc = cn - cm; dc = dc < 0 ? -dc : dc;
        float s = fmaf(sacc[i][r], scale, ab_s[dr * 14 + dc]);
        s = mok ? s : -1e30f;     // unconditional overwrite: kills any garbage-K NaN
        sacc[i][r] = s;
        float v = s;
#pragma unroll
        for (int o = 8; o > 0; o >>= 1) v = fmaxf(v, __shfl_xor(v, o));
        if (l15 == 0) pmax[w][n] = v;
      }
    }
  }
  __syncthreads();

  // ---- Phase B: combine partial maxes, compute rescale, pre-scale running sum ----
  if (tid < 208) {
    float mmax = pmax[0][tid];
    if (NMT == 4) {
      mmax = fmaxf(mmax, pmax[1][tid]);
      mmax = fmaxf(mmax, pmax[2][tid]);
      mmax = fmaxf(mmax, pmax[3][tid]);
    }
    const float mo = rmx[tid];
    const float mn = fmaxf(mo, mmax);
    rmx[tid] = mn;
    const float sc = __expf(mo - mn);
    scale_s[tid] = sc;
    rsum[tid] *= sc;
  }
  __syncthreads();

  // ---- Phase C: P = exp(S - mx_new) -> Pm (bf16), partial row-sums ----
  if (w < NMT) {
#pragma unroll
    for (int i = 0; i < 13; ++i) {
#pragma unroll
      for (int r = 0; r < 4; ++r) {
        const int n = i * 16 + quad * 4 + r;
        float e = __expf(sacc[i][r] - rmx[n]);
        Pm[n][w * 16 + l15] = f2b(e);
        float v = e;
#pragma unroll
        for (int o = 8; o > 0; o >>= 1) v += __shfl_xor(v, o);
        if (l15 == 0) psum[w][n] = v;
      }
    }
  } else if (NMT == 1) {
    // chunk 3 (m 192..223): waves 1-3 zero Pm cols 16..31 (pad m, contribute 0)
    const int lane63 = tid & 63;
    const int row = (w - 1) * 64 + lane63;     // 0..191
    ushort4 z; z.x = 0; z.y = 0; z.z = 0; z.w = 0;
    *(ushort4*)&Pm[row][16] = z; *(ushort4*)&Pm[row][20] = z;
    *(ushort4*)&Pm[row][24] = z; *(ushort4*)&Pm[row][28] = z;
    if (w == 1 && lane63 < 16) {
      const int r2 = 192 + lane63;
      *(ushort4*)&Pm[r2][16] = z; *(ushort4*)&Pm[r2][20] = z;
      *(ushort4*)&Pm[r2][24] = z; *(ushort4*)&Pm[r2][28] = z;
    }
  }
  __syncthreads();

  // ---- Phase D: fold chunk sums into running sum (208 threads, no barrier) ----
  if (tid < 208) {
    float s = psum[0][tid];
    if (NMT == 4) s += psum[1][tid] + psum[2][tid] + psum[3][tid];
    rsum[tid] += s;
  }

  // ---- Phase E: rescale acc, PV accumulate (barrier-free MFMA chain) ----
#pragma unroll
  for (int i = 0; i < 13; ++i) {
    const float sc = scale_s[i * 16 + l15];
    acc0[i] *= sc;
    acc1[i] *= sc;
  }
#pragma unroll
  for (int ks = 0; ks < NKS; ++ks) {
    s16x8 va0 = *(const s16x8*)(vgw + chunk * 64 + ks * 32);
    s16x8 va1 = *(const s16x8*)(vgw + 4 * VT_ST + chunk * 64 + ks * 32);
#pragma unroll
    for (int i = 0; i < 13; ++i) {
      s16x8 pb = *(const s16x8*)&Pm[i * 16 + l15][ks * 32 + quad * 8];
      acc0[i] = __builtin_amdgcn_mfma_f32_16x16x32_bf16(va0, pb, acc0[i], 0, 0, 0);
      acc1[i] = __builtin_amdgcn_mfma_f32_16x16x32_bf16(va1, pb, acc1[i], 0, 0, 0);
    }
  }
  __syncthreads();   // protects scale_s/pmax/Pm for next chunk; rsum for epilogue
}

__global__ __launch_bounds__(256, 2)
void attn_flash(const unsigned short* __restrict__ qkv,
                const unsigned short* __restrict__ vt,
                const float* __restrict__ ab,
                unsigned short* __restrict__ ctx) {
  __shared__ unsigned short Pm[208][PST];
  __shared__ float rmx[208], rsum[208], scale_s[208];
  __shared__ float pmax[4][208], psum[4][208];
  __shared__ float ab_s[196];

  const int bh = blockIdx.x;
  const int b = bh >> 3, h = bh & 7;
  const int tid = threadIdx.x;
  const int lane = tid & 63, w = tid >> 6;
  const int quad = lane >> 4, l15 = lane & 15;

  const unsigned short* qbase = qkv + (size_t)b * N_TOKENS * QKV_ST + h * 192;
  // permuted A-row: lane l15 loads physical d-row perm(l15) = (l15&3) + (l15>>2)*8
  const int pr = (l15 & 3) + ((l15 >> 2) << 3);
  const unsigned short* vgw = vt + ((size_t)bh * 128 + w * 32 + pr) * VT_ST + quad * 8;
  unsigned short* ctxp = ctx + (size_t)b * N_TOKENS * CTX_ST + h * 128;

  if (tid < 196) ab_s[tid] = ab[h * 196 + tid];
  if (tid < 208) { rmx[tid] = -1e30f; rsum[tid] = 0.f; }
  __syncthreads();

  f32x4 zero = {0.f, 0.f, 0.f, 0.f};
  f32x4 acc0[13], acc1[13];
#pragma unroll
  for (int i = 0; i < 13; ++i) { acc0[i] = zero; acc1[i] = zero; }

#pragma unroll 1
  for (int c = 0; c < 3; ++c)
    flash_chunk<4, 2>(c, qbase, vgw, ab_s, Pm, rmx, rsum, scale_s, pmax, psum,
                      acc0, acc1, tid, w, quad, l15);
  flash_chunk<1, 1>(3, qbase, vgw, ab_s, Pm, rmx, rsum, scale_s, pmax, psum,
                    acc0, acc1, tid, w, quad, l15);

  // ---- epilogue: lane holds d = w*32+quad*8+{0..7} for n = i*16+l15 ----
#pragma unroll
  for (int i = 0; i < 13; ++i) {
    const int n = i * 16 + l15;
    if (n < 196) {
      const float is = 1.0f / rsum[n];
      s16x8 o;
      o[0] = (short)f2b(acc0[i][0] * is); o[1] = (short)f2b(acc0[i][1] * is);
      o[2] = (short)f2b(acc0[i][2] * is); o[3] = (short)f2b(acc0[i][3] * is);
      o[4] = (short)f2b(acc1[i][0] * is); o[5] = (short)f2b(acc1[i][1] * is);
      o[6] = (short)f2b(acc1[i][2] * is); o[7] = (short)f2b(acc1[i][3] * is);
      *(s16x8*)(ctxp + (size_t)n * CTX_ST + w * 32 + quad * 8) = o;
    }
  }
}

extern "C" void kernel_launch(void* const* d_in, const int* in_sizes, int n_in,
                              void* d_out, int out_size, void* d_ws, size_t ws_size,
                              hipStream_t stream) {
  const float* x     = (const float*)d_in[0];
  const float* Wqkv  = (const float*)d_in[1];
  const float* bqkv  = (const float*)d_in[2];
  const float* Wproj = (const float*)d_in[3];
  const float* bproj = (const float*)d_in[4];
  const float* ab    = (const float*)d_in[5];
  float* out = (float*)d_out;

  const size_t szWq = 589824, szWp = 393216, szX = (size_t)B_SZ * N_TOKENS * DIM;
  const size_t fixedB = (szWq + szWp + szX) * 2;
  // per-batch: vt 8*128*224 + qkv 196*1536 + ctx 196*1024 elements (bf16)
  const size_t perB = (229376ULL + 301056ULL + 200704ULL) * 2;
  int Bs = 256;
  while (Bs > 32 && fixedB + (size_t)Bs * perB > ws_size) Bs >>= 1;

  unsigned short* Wqb  = (unsigned short*)d_ws;
  unsigned short* Wpb  = Wqb + szWq;
  unsigned short* xb   = Wpb + szWp;
  unsigned short* vtb  = xb + szX;
  unsigned short* qkvb = vtb + (size_t)Bs * 229376;
  unsigned short* ctxb = qkvb + (size_t)Bs * 301056;

  cvt_f32_bf16<<<dim3(576), dim3(256), 0, stream>>>(Wqkv, Wqb, (int)(szWq / 4));
  cvt_f32_bf16<<<dim3(384), dim3(256), 0, stream>>>(Wproj, Wpb, (int)(szWp / 4));
  cvt_f32_bf16<<<dim3(4096), dim3(256), 0, stream>>>(x, xb, (int)(szX / 4));

  const int nslice = B_SZ / Bs;
  const int Ms = Bs * N_TOKENS;
  for (int s = 0; s < nslice; ++s) {
    const unsigned short* xs = xb + (size_t)s * Ms * DIM;
    float* outs = out + (size_t)s * Ms * DIM;
    gemm_bf16_bt<1><<<dim3((Ms / 128) * (HID / 128)), dim3(256), 0, stream>>>(
        xs, Wqb, bqkv, qkvb, Ms, HID, DIM);
    transpose_v<<<dim3(Bs * 8 * 28), dim3(256), 0, stream>>>(qkvb, vtb);
    attn_flash<<<dim3(Bs * 8), dim3(256), 0, stream>>>(qkvb, vtb, ab, ctxb);
    gemm_bf16_bt<0><<<dim3((Ms / 128) * (DIM / 128)), dim3(256), 0, stream>>>(
        ctxb, Wpb, bproj, outs, Ms, DIM, CTX_ST);
  }
}

// Round 4
// 605.782 us; speedup vs baseline: 1.5809x; 1.5809x over previous
//
#include <hip/hip_runtime.h>
#include <math.h>

#define B_SZ 256
#define N_TOKENS 196
#define DIM 384
#define NH 8
#define QKV_ST 1536      // NH*(2*32+128)
#define HID 1536
#define CTX_ST 1024      // NH*128
#define VT_ST 208        // padded token stride of V^T (13*16)

typedef short s16x8_base __attribute__((ext_vector_type(8)));
typedef s16x8_base __attribute__((may_alias)) s16x8;
typedef float f32x4_base __attribute__((ext_vector_type(4)));
typedef f32x4_base __attribute__((may_alias)) f32x4;

__device__ inline unsigned short f2b(float f) {
  union { float f; unsigned int u; } v; v.f = f;
  unsigned int r = (v.u + 0x7FFFu + ((v.u >> 16) & 1u)) >> 16;   // RNE, finite inputs
  return (unsigned short)r;
}

#define GLDS16(g, l)                                                        \
  __builtin_amdgcn_global_load_lds(                                         \
      (__attribute__((address_space(1))) void*)(g),                         \
      (__attribute__((address_space(3))) void*)(l), 16, 0, 0)

// ---------------- fp32 -> bf16 convert (vectorized, grid-stride) ----------------
__global__ __launch_bounds__(256)
void cvt_f32_bf16(const float* __restrict__ in, unsigned short* __restrict__ out, int n4) {
  int i = blockIdx.x * 256 + threadIdx.x;
  const int stride = gridDim.x * 256;
  for (; i < n4; i += stride) {
    float4 v = ((const float4*)in)[i];
    ushort4 o;
    o.x = f2b(v.x); o.y = f2b(v.y); o.z = f2b(v.z); o.w = f2b(v.w);
    ((ushort4*)out)[i] = o;
  }
}

// ---------------- bf16 MFMA GEMM: C[M][N] = A[M][K] @ B[N][K]^T + bias ----------------
// 128x128 tile, BK=32, 256 threads, wave-tile 64x64 (4x4 of 16x16x32).
// Double-buffered global_load_lds staging (T3-minimum 2-phase): next tile's
// loads fly during current tile's ds_read+MFMA; one __syncthreads per tile.
// MFMA operands SWAPPED (acc = B^T*A form) so each lane holds 4 consecutive
// C-columns -> packed coalesced epilogue stores.
template <int OUT_BF16>
__global__ __launch_bounds__(256)
void gemm_bf16_bt(const unsigned short* __restrict__ A,
                  const unsigned short* __restrict__ Bm,
                  const float* __restrict__ bias,
                  void* __restrict__ C, int M, int N, int K) {
  __shared__ unsigned short As[2][128][32];
  __shared__ unsigned short Bs[2][128][32];
  const int tid = threadIdx.x;
  const int lane = tid & 63, wave = tid >> 6;
  const int quad = lane >> 4, l15 = lane & 15;
  const int ntile = N >> 7;
  const int bx = blockIdx.x % ntile, by = blockIdx.x / ntile;
  const int row0 = by << 7, col0 = bx << 7;

  // glds: wave w stages rows [w*32, w*32+32) of each matrix (2 calls x 16 rows).
  // lane -> row w*32 + c*16 + (lane>>2), elem (lane&3)*8; LDS dest linear.
  const int grow = lane >> 2, gcol = (lane & 3) << 3;
  const unsigned short* Ag = A + (size_t)(row0 + (wave << 5) + grow) * K + gcol;
  const unsigned short* Bg = Bm + (size_t)(col0 + (wave << 5) + grow) * K + gcol;

#define STAGE(bb, kk)                                                       \
  do {                                                                      \
    GLDS16(Ag + (kk), &As[bb][(wave << 5)][0]);                             \
    GLDS16(Ag + (kk) + (size_t)16 * K, &As[bb][(wave << 5) + 16][0]);       \
    GLDS16(Bg + (kk), &Bs[bb][(wave << 5)][0]);                             \
    GLDS16(Bg + (kk) + (size_t)16 * K, &Bs[bb][(wave << 5) + 16][0]);       \
  } while (0)

  const int wr = (wave >> 1) << 6, wc = (wave & 1) << 6;

  f32x4 zero = {0.f, 0.f, 0.f, 0.f};
  f32x4 acc[4][4];
#pragma unroll
  for (int i = 0; i < 4; ++i)
#pragma unroll
    for (int j = 0; j < 4; ++j) acc[i][j] = zero;

  const int nt = K >> 5;
  STAGE(0, 0);
  __syncthreads();                       // drains tile-0 loads (vmcnt 0 + barrier)

  int cur = 0;
#pragma unroll 1
  for (int t = 0; t < nt; ++t) {
    if (t + 1 < nt) STAGE(cur ^ 1, (t + 1) << 5);   // in flight during compute
    s16x8 af[4], bf[4];
#pragma unroll
    for (int i = 0; i < 4; ++i) {
      af[i] = *(const s16x8*)&As[cur][wr + i * 16 + l15][quad * 8];
      bf[i] = *(const s16x8*)&Bs[cur][wc + i * 16 + l15][quad * 8];
    }
#pragma unroll
    for (int i = 0; i < 4; ++i)
#pragma unroll
      for (int j = 0; j < 4; ++j)
        acc[i][j] = __builtin_amdgcn_mfma_f32_16x16x32_bf16(bf[j], af[i], acc[i][j], 0, 0, 0);
    __syncthreads();                     // drains next-tile loads + read fence
    cur ^= 1;
  }
#undef STAGE

  // epilogue: acc[i][j] row(quad*4+r) -> C-col wc+j*16+quad*4+r, col(l15) -> C-row wr+i*16+l15
#pragma unroll
  for (int j = 0; j < 4; ++j) {
    const int colb = col0 + wc + j * 16 + quad * 4;
    const f32x4 bj = *(const f32x4*)&bias[colb];
#pragma unroll
    for (int i = 0; i < 4; ++i) {
      const int row = row0 + wr + i * 16 + l15;
      f32x4 v = acc[i][j] + bj;
      if (OUT_BF16) {
        ushort4 o;
        o.x = f2b(v[0]); o.y = f2b(v[1]); o.z = f2b(v[2]); o.w = f2b(v[3]);
        *(ushort4*)((unsigned short*)C + (size_t)row * N + colb) = o;
      } else {
        *(f32x4*)((float*)C + (size_t)row * N + colb) = v;
      }
    }
  }
}

// ---------------- V -> V^T (per (b,h): [196][128] -> [128][208]) ----------------
__global__ __launch_bounds__(256)
void transpose_v(const unsigned short* __restrict__ qkv, unsigned short* __restrict__ vt) {
  __shared__ unsigned short ts[32][36];
  const int id = blockIdx.x;
  const int tile = id % 28;
  const int bh = id / 28;
  const int b = bh >> 3, h = bh & 7;
  const int nt = tile % 7, dt = tile / 7;
  const int n0 = nt * 32, d0 = dt * 32;
  const int t = threadIdx.x;
  {
    const int nl = t >> 3, dq = (t & 7) << 2;
    ushort4 v4; v4.x = 0; v4.y = 0; v4.z = 0; v4.w = 0;
    if (n0 + nl < 196)
      v4 = *(const ushort4*)(qkv + ((size_t)(b * 196 + n0 + nl) * QKV_ST + h * 192 + 64 + d0 + dq));
    ts[dq + 0][nl] = v4.x; ts[dq + 1][nl] = v4.y;
    ts[dq + 2][nl] = v4.z; ts[dq + 3][nl] = v4.w;
  }
  __syncthreads();
  {
    const int dl = t >> 3, nq = (t & 7) << 2;
    if (n0 + nq < VT_ST) {
      ushort4 o;
      o.x = ts[dl][nq + 0]; o.y = ts[dl][nq + 1];
      o.z = ts[dl][nq + 2]; o.w = ts[dl][nq + 3];
      *(ushort4*)(vt + ((size_t)(bh * 128 + d0 + dl) * VT_ST + n0 + nq)) = o;
    }
  }
}

// ---------------- MFMA attention: one block per (b,h) ----------------
// (byte-identical to the 587us round-0 version)
__global__ __launch_bounds__(256)
void attn_mfma(const unsigned short* __restrict__ qkv,
               const unsigned short* __restrict__ vt,
               const float* __restrict__ ab, const int* __restrict__ bidx,
               unsigned short* __restrict__ ctx) {
  __shared__ unsigned short Pm[112][232];   // P chunk: 112 rows, stride 232 (16B-aligned, 2-way banks)
  __shared__ unsigned short vts[128][32];   // V^T k-tile
  __shared__ float inv_s[112];

  const int bh = blockIdx.x;
  const int b = bh >> 3, h = bh & 7;
  const int tid = threadIdx.x;
  const int lane = tid & 63, w = tid >> 6;
  const int quad = lane >> 4, l15 = lane & 15;
  const float scale = 0.17677669529663687f;

  const unsigned short* qbase = qkv + (size_t)b * N_TOKENS * QKV_ST + h * 192;
  const unsigned short* vbase = vt + (size_t)bh * 128 * VT_ST;
  const float* abh = ab + h * 196;

  if (tid < 112) {
#pragma unroll
    for (int c = 208; c < 232; ++c) Pm[tid][c] = 0;   // zero mm-pad so pad cols contribute 0
  }

  const int srow = tid >> 1, soff = (tid & 1) << 4;   // V^T staging: 32B/thread
  const unsigned short* vg = vbase + (size_t)srow * VT_ST + soff;

  f32x4 zero = {0.f, 0.f, 0.f, 0.f};

  for (int chunk = 0; chunk < 2; ++chunk) {
    const int nbase = chunk * 112;
    __syncthreads();   // Pm/inv_s free (prev chunk done); pad-zero visible

    // ---- S phase: wave w owns local tile-rows {2w, 2w+1} (wave 3: one) ----
    const int ntr = (w < 3) ? 2 : 1;
    for (int t2 = 0; t2 < ntr; ++t2) {
      const int rowt = w * 32 + t2 * 16;
      s16x8 aq = *(const s16x8*)(qbase + (size_t)(nbase + rowt + l15) * QKV_ST + quad * 8);
      f32x4 sacc[13];
#pragma unroll
      for (int j = 0; j < 13; ++j) {
        s16x8 bk = *(const s16x8*)(qbase + (size_t)(j * 16 + l15) * QKV_ST + 32 + quad * 8);
        sacc[j] = __builtin_amdgcn_mfma_f32_16x16x32_bf16(aq, bk, zero, 0, 0, 0);
      }
      float mx[4] = {-1e30f, -1e30f, -1e30f, -1e30f};
#pragma unroll
      for (int j = 0; j < 13; ++j) {
        const int m = j * 16 + l15;
        const int mc = m < 196 ? m : 195;
#pragma unroll
        for (int r = 0; r < 4; ++r) {
          const int n = nbase + rowt + quad * 4 + r;
          const int nc = n < 196 ? n : 195;
          float s = sacc[j][r] * scale + abh[bidx[nc * 196 + mc]];
          s = (m < 196) ? s : -1e30f;
          sacc[j][r] = s;
          mx[r] = fmaxf(mx[r], s);
        }
      }
#pragma unroll
      for (int o = 8; o > 0; o >>= 1)
#pragma unroll
        for (int r = 0; r < 4; ++r) mx[r] = fmaxf(mx[r], __shfl_xor(mx[r], o));
      float sm[4] = {0.f, 0.f, 0.f, 0.f};
#pragma unroll
      for (int j = 0; j < 13; ++j)
#pragma unroll
        for (int r = 0; r < 4; ++r) {
          float e = __expf(sacc[j][r] - mx[r]);
          sm[r] += e;
          Pm[rowt + quad * 4 + r][j * 16 + l15] = f2b(e);
        }
#pragma unroll
      for (int o = 8; o > 0; o >>= 1)
#pragma unroll
        for (int r = 0; r < 4; ++r) sm[r] += __shfl_xor(sm[r], o);
      if (l15 == 0) {
#pragma unroll
        for (int r = 0; r < 4; ++r) inv_s[rowt + quad * 4 + r] = 1.f / sm[r];
      }
    }

    // ---- PV: wave w owns d-cols [w*32, w*32+32); 7 row-tiles x 2 col-tiles ----
    f32x4 pacc[7][2];
#pragma unroll
    for (int i = 0; i < 7; ++i) { pacc[i][0] = zero; pacc[i][1] = zero; }

    s16x8 v0 = *(const s16x8*)(vg + 0);
    s16x8 v1 = *(const s16x8*)(vg + 8);
    for (int ks = 0; ks < 7; ++ks) {
      __syncthreads();   // P/inv visible (ks=0); prev vts reads done
      *(s16x8*)&vts[srow][soff] = v0;
      *(s16x8*)&vts[srow][soff + 8] = v1;
      __syncthreads();   // vts ready
      if (ks < 6) {
        v0 = *(const s16x8*)(vg + (ks + 1) * 32);
        v1 = *(const s16x8*)(vg + (ks + 1) * 32 + 8);
      }
      s16x8 bf0 = *(const s16x8*)&vts[w * 32 + l15][quad * 8];
      s16x8 bf1 = *(const s16x8*)&vts[w * 32 + 16 + l15][quad * 8];
#pragma unroll
      for (int i = 0; i < 7; ++i) {
        s16x8 ap = *(const s16x8*)&Pm[i * 16 + l15][ks * 32 + quad * 8];
        pacc[i][0] = __builtin_amdgcn_mfma_f32_16x16x32_bf16(ap, bf0, pacc[i][0], 0, 0, 0);
        pacc[i][1] = __builtin_amdgcn_mfma_f32_16x16x32_bf16(ap, bf1, pacc[i][1], 0, 0, 0);
      }
    }

    // ---- epilogue: normalize + store (bf16 ctx) ----
#pragma unroll
    for (int i = 0; i < 7; ++i) {
#pragma unroll
      for (int jl = 0; jl < 2; ++jl) {
        const int d = w * 32 + jl * 16 + l15;
#pragma unroll
        for (int r = 0; r < 4; ++r) {
          const int nl = i * 16 + quad * 4 + r;
          const int n = nbase + nl;
          if (n < 196) {
            float v = pacc[i][jl][r] * inv_s[nl];
            ctx[(size_t)(b * N_TOKENS + n) * CTX_ST + h * 128 + d] = f2b(v);
          }
        }
      }
    }
  }
}

extern "C" void kernel_launch(void* const* d_in, const int* in_sizes, int n_in,
                              void* d_out, int out_size, void* d_ws, size_t ws_size,
                              hipStream_t stream) {
  const float* x     = (const float*)d_in[0];
  const float* Wqkv  = (const float*)d_in[1];
  const float* bqkv  = (const float*)d_in[2];
  const float* Wproj = (const float*)d_in[3];
  const float* bproj = (const float*)d_in[4];
  const float* ab    = (const float*)d_in[5];
  const int*   bidx  = (const int*)d_in[6];
  float* out = (float*)d_out;

  const size_t szWq = 589824, szWp = 393216, szX = (size_t)B_SZ * N_TOKENS * DIM;
  const size_t fixedB = (szWq + szWp + szX) * 2;
  // per-batch: vt 8*128*208 + qkv 196*1536 + ctx 196*1024 elements (bf16)
  const size_t perB = (212992ULL + 301056ULL + 200704ULL) * 2;
  int Bs = 256;
  while (Bs > 32 && fixedB + (size_t)Bs * perB > ws_size) Bs >>= 1;

  unsigned short* Wqb  = (unsigned short*)d_ws;
  unsigned short* Wpb  = Wqb + szWq;
  unsigned short* xb   = Wpb + szWp;
  unsigned short* vtb  = xb + szX;
  unsigned short* qkvb = vtb + (size_t)Bs * 212992;
  unsigned short* ctxb = qkvb + (size_t)Bs * 301056;

  cvt_f32_bf16<<<dim3(576), dim3(256), 0, stream>>>(Wqkv, Wqb, (int)(szWq / 4));
  cvt_f32_bf16<<<dim3(384), dim3(256), 0, stream>>>(Wproj, Wpb, (int)(szWp / 4));
  cvt_f32_bf16<<<dim3(4096), dim3(256), 0, stream>>>(x, xb, (int)(szX / 4));

  const int nslice = B_SZ / Bs;
  const int Ms = Bs * N_TOKENS;
  for (int s = 0; s < nslice; ++s) {
    const unsigned short* xs = xb + (size_t)s * Ms * DIM;
    float* outs = out + (size_t)s * Ms * DIM;
    gemm_bf16_bt<1><<<dim3((Ms / 128) * (HID / 128)), dim3(256), 0, stream>>>(
        xs, Wqb, bqkv, qkvb, Ms, HID, DIM);
    transpose_v<<<dim3(Bs * 8 * 28), dim3(256), 0, stream>>>(qkvb, vtb);
    attn_mfma<<<dim3(Bs * 8), dim3(256), 0, stream>>>(qkvb, vtb, ab, bidx, ctxb);
    gemm_bf16_bt<0><<<dim3((Ms / 128) * (DIM / 128)), dim3(256), 0, stream>>>(
        ctxb, Wpb, bproj, outs, Ms, DIM, CTX_ST);
  }
}

// Round 5
// 580.841 us; speedup vs baseline: 1.6488x; 1.0429x over previous
//
#include <hip/hip_runtime.h>
#include <math.h>

#define B_SZ 256
#define N_TOKENS 196
#define DIM 384
#define NH 8
#define QKV_ST 1536      // NH*(2*32+128)
#define HID 1536
#define CTX_ST 1024      // NH*128
#define VT_ST 208        // padded token stride of V^T (13*16)

typedef short s16x8_base __attribute__((ext_vector_type(8)));
typedef s16x8_base __attribute__((may_alias)) s16x8;
typedef float f32x4_base __attribute__((ext_vector_type(4)));
typedef f32x4_base __attribute__((may_alias)) f32x4;

__device__ inline unsigned short f2b(float f) {
  union { float f; unsigned int u; } v; v.f = f;
  unsigned int r = (v.u + 0x7FFFu + ((v.u >> 16) & 1u)) >> 16;   // RNE, finite inputs
  return (unsigned short)r;
}

// ---------------- fp32 -> bf16 convert (vectorized, grid-stride) ----------------
__global__ __launch_bounds__(256)
void cvt_f32_bf16(const float* __restrict__ in, unsigned short* __restrict__ out, int n4) {
  int i = blockIdx.x * 256 + threadIdx.x;
  const int stride = gridDim.x * 256;
  for (; i < n4; i += stride) {
    float4 v = ((const float4*)in)[i];
    ushort4 o;
    o.x = f2b(v.x); o.y = f2b(v.y); o.z = f2b(v.z); o.w = f2b(v.w);
    ((ushort4*)out)[i] = o;
  }
}

// ---------------- bf16 MFMA GEMM: C[M][N] = A[M][K] @ B[N][K]^T + bias ----------------
// 128x128 tile, BK=32, 256 threads, wave-tile 64x64 (4x4 of 16x16x32).
// R0 reg-staged double-buffer prefetch (known-good). MFMA operands SWAPPED
// (acc holds C^T fragments) so each lane owns 4 consecutive C-columns ->
// packed, coalesced epilogue stores (verified layout: R4 passed).
template <int OUT_BF16>
__global__ __launch_bounds__(256)
void gemm_bf16_bt(const unsigned short* __restrict__ A,
                  const unsigned short* __restrict__ Bm,
                  const float* __restrict__ bias,
                  void* __restrict__ C, int M, int N, int K) {
  __shared__ unsigned short As[128][32];
  __shared__ unsigned short Bs[128][32];
  const int tid = threadIdx.x;
  const int lane = tid & 63, wave = tid >> 6;
  const int quad = lane >> 4, l15 = lane & 15;
  const int ntile = N >> 7;
  const int bx = blockIdx.x % ntile, by = blockIdx.x / ntile;
  const int row0 = by << 7, col0 = bx << 7;

  const int srow = tid >> 1, soff = (tid & 1) << 4;   // staging: 32B per thread
  const unsigned short* Ag = A + (size_t)(row0 + srow) * K + soff;
  const unsigned short* Bg = Bm + (size_t)(col0 + srow) * K + soff;

  const int wr = (wave >> 1) << 6, wc = (wave & 1) << 6;

  f32x4 zero = {0.f, 0.f, 0.f, 0.f};
  f32x4 acc[4][4];
#pragma unroll
  for (int i = 0; i < 4; ++i)
#pragma unroll
    for (int j = 0; j < 4; ++j) acc[i][j] = zero;

  s16x8 a0 = *(const s16x8*)(Ag + 0);
  s16x8 a1 = *(const s16x8*)(Ag + 8);
  s16x8 b0 = *(const s16x8*)(Bg + 0);
  s16x8 b1 = *(const s16x8*)(Bg + 8);

  for (int k0 = 0; k0 < K; k0 += 32) {
    __syncthreads();
    *(s16x8*)&As[srow][soff] = a0;
    *(s16x8*)&As[srow][soff + 8] = a1;
    *(s16x8*)&Bs[srow][soff] = b0;
    *(s16x8*)&Bs[srow][soff + 8] = b1;
    __syncthreads();
    if (k0 + 32 < K) {
      a0 = *(const s16x8*)(Ag + k0 + 32);
      a1 = *(const s16x8*)(Ag + k0 + 40);
      b0 = *(const s16x8*)(Bg + k0 + 32);
      b1 = *(const s16x8*)(Bg + k0 + 40);
    }
    s16x8 af[4], bf[4];
#pragma unroll
    for (int i = 0; i < 4; ++i) {
      af[i] = *(const s16x8*)&As[wr + i * 16 + l15][quad * 8];
      bf[i] = *(const s16x8*)&Bs[wc + i * 16 + l15][quad * 8];
    }
#pragma unroll
    for (int i = 0; i < 4; ++i)
#pragma unroll
      for (int j = 0; j < 4; ++j)
        acc[i][j] = __builtin_amdgcn_mfma_f32_16x16x32_bf16(bf[j], af[i], acc[i][j], 0, 0, 0);
  }

  // epilogue: acc[i][j]: C-row = wr+i*16+l15, C-cols = wc+j*16+quad*4 + {0..3}
#pragma unroll
  for (int j = 0; j < 4; ++j) {
    const int colb = col0 + wc + j * 16 + quad * 4;
    const f32x4 bj = *(const f32x4*)&bias[colb];
#pragma unroll
    for (int i = 0; i < 4; ++i) {
      const int row = row0 + wr + i * 16 + l15;
      f32x4 v = acc[i][j] + bj;
      if (OUT_BF16) {
        ushort4 o;
        o.x = f2b(v[0]); o.y = f2b(v[1]); o.z = f2b(v[2]); o.w = f2b(v[3]);
        *(ushort4*)((unsigned short*)C + (size_t)row * N + colb) = o;
      } else {
        *(f32x4*)((float*)C + (size_t)row * N + colb) = v;
      }
    }
  }
}

// ---------------- V -> V^T (per (b,h): [196][128] -> [128][208]) ----------------
__global__ __launch_bounds__(256)
void transpose_v(const unsigned short* __restrict__ qkv, unsigned short* __restrict__ vt) {
  __shared__ unsigned short ts[32][36];
  const int id = blockIdx.x;
  const int tile = id % 28;
  const int bh = id / 28;
  const int b = bh >> 3, h = bh & 7;
  const int nt = tile % 7, dt = tile / 7;
  const int n0 = nt * 32, d0 = dt * 32;
  const int t = threadIdx.x;
  {
    const int nl = t >> 3, dq = (t & 7) << 2;
    ushort4 v4; v4.x = 0; v4.y = 0; v4.z = 0; v4.w = 0;
    if (n0 + nl < 196)
      v4 = *(const ushort4*)(qkv + ((size_t)(b * 196 + n0 + nl) * QKV_ST + h * 192 + 64 + d0 + dq));
    ts[dq + 0][nl] = v4.x; ts[dq + 1][nl] = v4.y;
    ts[dq + 2][nl] = v4.z; ts[dq + 3][nl] = v4.w;
  }
  __syncthreads();
  {
    const int dl = t >> 3, nq = (t & 7) << 2;
    if (n0 + nq < VT_ST) {
      ushort4 o;
      o.x = ts[dl][nq + 0]; o.y = ts[dl][nq + 1];
      o.z = ts[dl][nq + 2]; o.w = ts[dl][nq + 3];
      *(ushort4*)(vt + ((size_t)(bh * 128 + d0 + dl) * VT_ST + n0 + nq)) = o;
    }
  }
}

// ---------------- MFMA attention: one block per (b,h), 112-row chunks ----------------
// S phase: R0 structure (q/k frags from global, bidx/ab gather, wave-local softmax).
// PV: TRANSPOSED, V^T A-operand frags read DIRECTLY from global with permuted
// d-rows (layout verified in R1): out^T = mfma(va, pb). No LDS V staging ->
// 2 barriers/chunk instead of 15; packed 16B ctx stores. LDS 52.4KB -> 3 blocks/CU.
__global__ __launch_bounds__(256)
void attn_mfma(const unsigned short* __restrict__ qkv,
               const unsigned short* __restrict__ vt,
               const float* __restrict__ ab, const int* __restrict__ bidx,
               unsigned short* __restrict__ ctx) {
  __shared__ unsigned short Pm[112][232];   // P chunk; cols 208..231 zeroed (m-pad)
  __shared__ float inv_s[112];

  const int bh = blockIdx.x;
  const int b = bh >> 3, h = bh & 7;
  const int tid = threadIdx.x;
  const int lane = tid & 63, w = tid >> 6;
  const int quad = lane >> 4, l15 = lane & 15;
  const float scale = 0.17677669529663687f;

  const unsigned short* qbase = qkv + (size_t)b * N_TOKENS * QKV_ST + h * 192;
  const float* abh = ab + h * 196;
  // permuted A-row: lane l15 loads physical d-row perm(l15) = (l15&3) + (l15>>2)*8
  const int pr = (l15 & 3) + ((l15 >> 2) << 3);
  const unsigned short* vgw = vt + ((size_t)bh * 128 + w * 32 + pr) * VT_ST + quad * 8;
  unsigned short* ctxp = ctx + (size_t)b * N_TOKENS * CTX_ST + h * 128;

  if (tid < 112) {
#pragma unroll
    for (int c = 208; c < 232; ++c) Pm[tid][c] = 0;   // zero m-pad: pad cols contribute 0
  }

  f32x4 zero = {0.f, 0.f, 0.f, 0.f};

  for (int chunk = 0; chunk < 2; ++chunk) {
    const int nbase = chunk * 112;
    __syncthreads();   // Pm/inv_s free (prev chunk PV reads done); pad-zero visible

    // ---- S phase: wave w owns local tile-rows {2w, 2w+1} (wave 3: one) ----
    const int ntr = (w < 3) ? 2 : 1;
    for (int t2 = 0; t2 < ntr; ++t2) {
      const int rowt = w * 32 + t2 * 16;
      s16x8 aq = *(const s16x8*)(qbase + (size_t)(nbase + rowt + l15) * QKV_ST + quad * 8);
      f32x4 sacc[13];
#pragma unroll
      for (int j = 0; j < 13; ++j) {
        s16x8 bk = *(const s16x8*)(qbase + (size_t)(j * 16 + l15) * QKV_ST + 32 + quad * 8);
        sacc[j] = __builtin_amdgcn_mfma_f32_16x16x32_bf16(aq, bk, zero, 0, 0, 0);
      }
      float mx[4] = {-1e30f, -1e30f, -1e30f, -1e30f};
#pragma unroll
      for (int j = 0; j < 13; ++j) {
        const int m = j * 16 + l15;
        const int mc = m < 196 ? m : 195;
#pragma unroll
        for (int r = 0; r < 4; ++r) {
          const int n = nbase + rowt + quad * 4 + r;
          const int nc = n < 196 ? n : 195;
          float s = sacc[j][r] * scale + abh[bidx[nc * 196 + mc]];
          s = (m < 196) ? s : -1e30f;
          sacc[j][r] = s;
          mx[r] = fmaxf(mx[r], s);
        }
      }
#pragma unroll
      for (int o = 8; o > 0; o >>= 1)
#pragma unroll
        for (int r = 0; r < 4; ++r) mx[r] = fmaxf(mx[r], __shfl_xor(mx[r], o));
      float sm[4] = {0.f, 0.f, 0.f, 0.f};
#pragma unroll
      for (int j = 0; j < 13; ++j)
#pragma unroll
        for (int r = 0; r < 4; ++r) {
          float e = __expf(sacc[j][r] - mx[r]);
          sm[r] += e;
          Pm[rowt + quad * 4 + r][j * 16 + l15] = f2b(e);
        }
#pragma unroll
      for (int o = 8; o > 0; o >>= 1)
#pragma unroll
        for (int r = 0; r < 4; ++r) sm[r] += __shfl_xor(sm[r], o);
      if (l15 == 0) {
#pragma unroll
        for (int r = 0; r < 4; ++r) inv_s[rowt + quad * 4 + r] = 1.f / sm[r];
      }
    }
    __syncthreads();   // Pm + inv_s ready

    // ---- PV (transposed, barrier-free): wave owns d in [w*32, w*32+32) ----
    f32x4 a0[7], a1[7];
#pragma unroll
    for (int i = 0; i < 7; ++i) { a0[i] = zero; a1[i] = zero; }
    s16x8 va0 = *(const s16x8*)(vgw + 0);            // rows w*32 + pr
    s16x8 va1 = *(const s16x8*)(vgw + 4 * VT_ST);    // rows w*32 + pr + 4
#pragma unroll
    for (int ks = 0; ks < 7; ++ks) {
      s16x8 nva0, nva1;
      if (ks < 6) {
        nva0 = *(const s16x8*)(vgw + (ks + 1) * 32);
        nva1 = *(const s16x8*)(vgw + 4 * VT_ST + (ks + 1) * 32);
      }
#pragma unroll
      for (int i = 0; i < 7; ++i) {
        s16x8 pb = *(const s16x8*)&Pm[i * 16 + l15][ks * 32 + quad * 8];
        a0[i] = __builtin_amdgcn_mfma_f32_16x16x32_bf16(va0, pb, a0[i], 0, 0, 0);
        a1[i] = __builtin_amdgcn_mfma_f32_16x16x32_bf16(va1, pb, a1[i], 0, 0, 0);
      }
      va0 = nva0; va1 = nva1;
    }

    // ---- epilogue: lane holds d = w*32 + quad*8 + {0..7} for n = nbase+i*16+l15 ----
#pragma unroll
    for (int i = 0; i < 7; ++i) {
      const int n = nbase + i * 16 + l15;
      if (n < 196) {
        const float is = inv_s[i * 16 + l15];
        s16x8 o;
        o[0] = (short)f2b(a0[i][0] * is); o[1] = (short)f2b(a0[i][1] * is);
        o[2] = (short)f2b(a0[i][2] * is); o[3] = (short)f2b(a0[i][3] * is);
        o[4] = (short)f2b(a1[i][0] * is); o[5] = (short)f2b(a1[i][1] * is);
        o[6] = (short)f2b(a1[i][2] * is); o[7] = (short)f2b(a1[i][3] * is);
        *(s16x8*)(ctxp + (size_t)n * CTX_ST + w * 32 + quad * 8) = o;
      }
    }
  }
}

extern "C" void kernel_launch(void* const* d_in, const int* in_sizes, int n_in,
                              void* d_out, int out_size, void* d_ws, size_t ws_size,
                              hipStream_t stream) {
  const float* x     = (const float*)d_in[0];
  const float* Wqkv  = (const float*)d_in[1];
  const float* bqkv  = (const float*)d_in[2];
  const float* Wproj = (const float*)d_in[3];
  const float* bproj = (const float*)d_in[4];
  const float* ab    = (const float*)d_in[5];
  const int*   bidx  = (const int*)d_in[6];
  float* out = (float*)d_out;

  const size_t szWq = 589824, szWp = 393216, szX = (size_t)B_SZ * N_TOKENS * DIM;
  const size_t fixedB = (szWq + szWp + szX) * 2;
  // per-batch: vt 8*128*208 + qkv 196*1536 + ctx 196*1024 elements (bf16)
  const size_t perB = (212992ULL + 301056ULL + 200704ULL) * 2;
  int Bs = 256;
  while (Bs > 32 && fixedB + (size_t)Bs * perB > ws_size) Bs >>= 1;

  unsigned short* Wqb  = (unsigned short*)d_ws;
  unsigned short* Wpb  = Wqb + szWq;
  unsigned short* xb   = Wpb + szWp;
  unsigned short* vtb  = xb + szX;
  unsigned short* qkvb = vtb + (size_t)Bs * 212992;
  unsigned short* ctxb = qkvb + (size_t)Bs * 301056;

  cvt_f32_bf16<<<dim3(576), dim3(256), 0, stream>>>(Wqkv, Wqb, (int)(szWq / 4));
  cvt_f32_bf16<<<dim3(384), dim3(256), 0, stream>>>(Wproj, Wpb, (int)(szWp / 4));
  cvt_f32_bf16<<<dim3(4096), dim3(256), 0, stream>>>(x, xb, (int)(szX / 4));

  const int nslice = B_SZ / Bs;
  const int Ms = Bs * N_TOKENS;
  for (int s = 0; s < nslice; ++s) {
    const unsigned short* xs = xb + (size_t)s * Ms * DIM;
    float* outs = out + (size_t)s * Ms * DIM;
    gemm_bf16_bt<1><<<dim3((Ms / 128) * (HID / 128)), dim3(256), 0, stream>>>(
        xs, Wqb, bqkv, qkvb, Ms, HID, DIM);
    transpose_v<<<dim3(Bs * 8 * 28), dim3(256), 0, stream>>>(qkvb, vtb);
    attn_mfma<<<dim3(Bs * 8), dim3(256), 0, stream>>>(qkvb, vtb, ab, bidx, ctxb);
    gemm_bf16_bt<0><<<dim3((Ms / 128) * (DIM / 128)), dim3(256), 0, stream>>>(
        ctxb, Wpb, bproj, outs, Ms, DIM, CTX_ST);
  }
}

// Round 6
// 526.066 us; speedup vs baseline: 1.8205x; 1.1041x over previous
//
#include <hip/hip_runtime.h>
#include <math.h>

#define B_SZ 256
#define N_TOKENS 196
#define DIM 384
#define NH 8
#define QKV_ST 1536      // NH*(2*32+128)
#define HID 1536
#define CTX_ST 1024      // NH*128
#define VT_ST 208        // padded token stride of V^T (13*16)

typedef short s16x8_base __attribute__((ext_vector_type(8)));
typedef s16x8_base __attribute__((may_alias)) s16x8;
typedef float f32x4_base __attribute__((ext_vector_type(4)));
typedef f32x4_base __attribute__((may_alias)) f32x4;

__device__ inline unsigned short f2b(float f) {
  union { float f; unsigned int u; } v; v.f = f;
  unsigned int r = (v.u + 0x7FFFu + ((v.u >> 16) & 1u)) >> 16;   // RNE, finite inputs
  return (unsigned short)r;
}

// ---------------- fp32 -> bf16 convert (vectorized, grid-stride) ----------------
__global__ __launch_bounds__(256)
void cvt_f32_bf16(const float* __restrict__ in, unsigned short* __restrict__ out, int n4) {
  int i = blockIdx.x * 256 + threadIdx.x;
  const int stride = gridDim.x * 256;
  for (; i < n4; i += stride) {
    float4 v = ((const float4*)in)[i];
    ushort4 o;
    o.x = f2b(v.x); o.y = f2b(v.y); o.z = f2b(v.z); o.w = f2b(v.w);
    ((ushort4*)out)[i] = o;
  }
}

// ---------------- zero V^T pad columns (tokens 196..207), once ----------------
__global__ __launch_bounds__(256)
void zero_vt_pad(unsigned short* __restrict__ vt, int total) {
  int i = blockIdx.x * 256 + threadIdx.x;    // over nbh*128*12
  if (i < total) {
    const int c = i % 12, rr = i / 12;       // rr = bh*128 + d
    vt[(size_t)rr * VT_ST + 196 + c] = 0;
  }
}

// ---------------- bf16 MFMA GEMM: C[M][N] = A[M][K] @ B[N][K]^T + bias ----------------
// 128x128 tile, BK=32, 256 threads, wave-tile 64x64 (4x4 of 16x16x32).
// Reg-staged double-buffer prefetch (known-good). Operands swapped (acc = C^T
// frags): lane owns 4 consecutive C-cols -> packed stores.
// MODE 0: f32 out + bias (proj). MODE 1: qkv out — Q/K cols packed bf16 to C;
// V cols written TRANSPOSED to vt (fuses transpose_v kernel; values identical).
template <int MODE>
__global__ __launch_bounds__(256)
void gemm_bf16_bt(const unsigned short* __restrict__ A,
                  const unsigned short* __restrict__ Bm,
                  const float* __restrict__ bias,
                  void* __restrict__ C, unsigned short* __restrict__ vt,
                  int M, int N, int K) {
  __shared__ unsigned short As[128][32];
  __shared__ unsigned short Bs[128][32];
  const int tid = threadIdx.x;
  const int lane = tid & 63, wave = tid >> 6;
  const int quad = lane >> 4, l15 = lane & 15;
  const int ntile = N >> 7;
  const int bx = blockIdx.x % ntile, by = blockIdx.x / ntile;
  const int row0 = by << 7, col0 = bx << 7;

  const int srow = tid >> 1, soff = (tid & 1) << 4;   // staging: 32B per thread
  const unsigned short* Ag = A + (size_t)(row0 + srow) * K + soff;
  const unsigned short* Bg = Bm + (size_t)(col0 + srow) * K + soff;

  const int wr = (wave >> 1) << 6, wc = (wave & 1) << 6;

  f32x4 zero = {0.f, 0.f, 0.f, 0.f};
  f32x4 acc[4][4];
#pragma unroll
  for (int i = 0; i < 4; ++i)
#pragma unroll
    for (int j = 0; j < 4; ++j) acc[i][j] = zero;

  s16x8 a0 = *(const s16x8*)(Ag + 0);
  s16x8 a1 = *(const s16x8*)(Ag + 8);
  s16x8 b0 = *(const s16x8*)(Bg + 0);
  s16x8 b1 = *(const s16x8*)(Bg + 8);

  for (int k0 = 0; k0 < K; k0 += 32) {
    __syncthreads();
    *(s16x8*)&As[srow][soff] = a0;
    *(s16x8*)&As[srow][soff + 8] = a1;
    *(s16x8*)&Bs[srow][soff] = b0;
    *(s16x8*)&Bs[srow][soff + 8] = b1;
    __syncthreads();
    if (k0 + 32 < K) {
      a0 = *(const s16x8*)(Ag + k0 + 32);
      a1 = *(const s16x8*)(Ag + k0 + 40);
      b0 = *(const s16x8*)(Bg + k0 + 32);
      b1 = *(const s16x8*)(Bg + k0 + 40);
    }
    s16x8 af[4], bf[4];
#pragma unroll
    for (int i = 0; i < 4; ++i) {
      af[i] = *(const s16x8*)&As[wr + i * 16 + l15][quad * 8];
      bf[i] = *(const s16x8*)&Bs[wc + i * 16 + l15][quad * 8];
    }
#pragma unroll
    for (int i = 0; i < 4; ++i)
#pragma unroll
      for (int j = 0; j < 4; ++j)
        acc[i][j] = __builtin_amdgcn_mfma_f32_16x16x32_bf16(bf[j], af[i], acc[i][j], 0, 0, 0);
  }

  // epilogue: acc[i][j]: C-row = wr+i*16+l15, C-cols = wc+j*16+quad*4 + {0..3}
#pragma unroll
  for (int j = 0; j < 4; ++j) {
    const int colb = col0 + wc + j * 16 + quad * 4;
    const f32x4 bj = *(const f32x4*)&bias[colb];
    if (MODE == 0) {
#pragma unroll
      for (int i = 0; i < 4; ++i) {
        const int row = row0 + wr + i * 16 + l15;
        f32x4 v = acc[i][j] + bj;
        *(f32x4*)((float*)C + (size_t)row * N + colb) = v;
      }
    } else {
      const int hh = colb / 192;
      const int c192 = colb - hh * 192;
      if (c192 < 64) {
        // Q/K columns: packed bf16 into qkv
#pragma unroll
        for (int i = 0; i < 4; ++i) {
          const int row = row0 + wr + i * 16 + l15;
          f32x4 v = acc[i][j] + bj;
          ushort4 o;
          o.x = f2b(v[0]); o.y = f2b(v[1]); o.z = f2b(v[2]); o.w = f2b(v[3]);
          *(ushort4*)((unsigned short*)C + (size_t)row * N + colb) = o;
        }
      } else {
        // V columns: transposed into vt[bh*128+d][n]  (lanes -> contiguous n)
        const int d = c192 - 64;
#pragma unroll
        for (int i = 0; i < 4; ++i) {
          const int row = row0 + wr + i * 16 + l15;
          const int bl = row / 196;
          const int n = row - bl * 196;
          f32x4 v = acc[i][j] + bj;
          unsigned short* vp = vt + ((size_t)((bl * 8 + hh) * 128 + d)) * VT_ST + n;
#pragma unroll
          for (int r = 0; r < 4; ++r) vp[(size_t)r * VT_ST] = f2b(v[r]);
        }
      }
    }
  }
}

// ---------------- MFMA attention: one block per (b,h), 112-row chunks ----------------
// S phase: q/k frags from global, ARITHMETIC bias (idx = |dr|*14+|dc|, ab_s in
// LDS) replacing the 2-level bidx->ab gather chain. PV: transposed, V^T frags
// direct from global (permuted d-rows); 2 barriers/chunk; packed 16B ctx stores.
// LDS 53.2KB -> exactly 3 blocks/CU (keeps working set L2-resident — R2/R3
// showed higher concurrency thrashes L2 and regresses).
__global__ __launch_bounds__(256)
void attn_mfma(const unsigned short* __restrict__ qkv,
               const unsigned short* __restrict__ vt,
               const float* __restrict__ ab,
               unsigned short* __restrict__ ctx) {
  __shared__ unsigned short Pm[112][232];   // P chunk; cols 208..231 zeroed (m-pad)
  __shared__ float inv_s[112];
  __shared__ float ab_s[196];

  const int bh = blockIdx.x;
  const int b = bh >> 3, h = bh & 7;
  const int tid = threadIdx.x;
  const int lane = tid & 63, w = tid >> 6;
  const int quad = lane >> 4, l15 = lane & 15;
  const float scale = 0.17677669529663687f;

  const unsigned short* qbase = qkv + (size_t)b * N_TOKENS * QKV_ST + h * 192;
  // permuted A-row: lane l15 loads physical d-row perm(l15) = (l15&3) + (l15>>2)*8
  const int pr = (l15 & 3) + ((l15 >> 2) << 3);
  const unsigned short* vgw = vt + ((size_t)bh * 128 + w * 32 + pr) * VT_ST + quad * 8;
  unsigned short* ctxp = ctx + (size_t)b * N_TOKENS * CTX_ST + h * 128;

  if (tid < 196) ab_s[tid] = ab[h * 196 + tid];
  if (tid < 112) {
#pragma unroll
    for (int c = 208; c < 232; ++c) Pm[tid][c] = 0;   // zero m-pad: pad cols contribute 0
  }

  f32x4 zero = {0.f, 0.f, 0.f, 0.f};

  for (int chunk = 0; chunk < 2; ++chunk) {
    const int nbase = chunk * 112;
    __syncthreads();   // Pm/inv_s free (prev chunk PV reads done); ab_s/pad visible

    // ---- S phase: wave w owns local tile-rows {2w, 2w+1} (wave 3: one) ----
    const int ntr = (w < 3) ? 2 : 1;
    for (int t2 = 0; t2 < ntr; ++t2) {
      const int rowt = w * 32 + t2 * 16;
      s16x8 aq = *(const s16x8*)(qbase + (size_t)(nbase + rowt + l15) * QKV_ST + quad * 8);
      f32x4 sacc[13];
#pragma unroll
      for (int j = 0; j < 13; ++j) {
        s16x8 bk = *(const s16x8*)(qbase + (size_t)(j * 16 + l15) * QKV_ST + 32 + quad * 8);
        sacc[j] = __builtin_amdgcn_mfma_f32_16x16x32_bf16(aq, bk, zero, 0, 0, 0);
      }
      int rn4[4], cn4[4];
#pragma unroll
      for (int r = 0; r < 4; ++r) {
        const int n = nbase + rowt + quad * 4 + r;
        const int nn = n < 196 ? n : 195;
        rn4[r] = nn / 14;
        cn4[r] = nn - rn4[r] * 14;
      }
      float mx[4] = {-1e30f, -1e30f, -1e30f, -1e30f};
#pragma unroll
      for (int j = 0; j < 13; ++j) {
        const int m = j * 16 + l15;
        const int mc = m < 196 ? m : 195;
        const int rm = mc / 14, cm = mc - rm * 14;
#pragma unroll
        for (int r = 0; r < 4; ++r) {
          int dr = rn4[r] - rm; dr = dr < 0 ? -dr : dr;
          int dc = cn4[r] - cm; dc = dc < 0 ? -dc : dc;
          float s = fmaf(sacc[j][r], scale, ab_s[dr * 14 + dc]);
          s = (m < 196) ? s : -1e30f;    // unconditional overwrite: kills garbage-K NaN
          sacc[j][r] = s;
          mx[r] = fmaxf(mx[r], s);
        }
      }
#pragma unroll
      for (int o = 8; o > 0; o >>= 1)
#pragma unroll
        for (int r = 0; r < 4; ++r) mx[r] = fmaxf(mx[r], __shfl_xor(mx[r], o));
      float sm[4] = {0.f, 0.f, 0.f, 0.f};
#pragma unroll
      for (int j = 0; j < 13; ++j)
#pragma unroll
        for (int r = 0; r < 4; ++r) {
          float e = __expf(sacc[j][r] - mx[r]);
          sm[r] += e;
          Pm[rowt + quad * 4 + r][j * 16 + l15] = f2b(e);
        }
#pragma unroll
      for (int o = 8; o > 0; o >>= 1)
#pragma unroll
        for (int r = 0; r < 4; ++r) sm[r] += __shfl_xor(sm[r], o);
      if (l15 == 0) {
#pragma unroll
        for (int r = 0; r < 4; ++r) inv_s[rowt + quad * 4 + r] = 1.f / sm[r];
      }
    }
    __syncthreads();   // Pm + inv_s ready

    // ---- PV (transposed, barrier-free): wave owns d in [w*32, w*32+32) ----
    f32x4 a0[7], a1[7];
#pragma unroll
    for (int i = 0; i < 7; ++i) { a0[i] = zero; a1[i] = zero; }
    s16x8 va0 = *(const s16x8*)(vgw + 0);            // rows w*32 + pr
    s16x8 va1 = *(const s16x8*)(vgw + 4 * VT_ST);    // rows w*32 + pr + 4
#pragma unroll
    for (int ks = 0; ks < 7; ++ks) {
      s16x8 nva0, nva1;
      if (ks < 6) {
        nva0 = *(const s16x8*)(vgw + (ks + 1) * 32);
        nva1 = *(const s16x8*)(vgw + 4 * VT_ST + (ks + 1) * 32);
      }
#pragma unroll
      for (int i = 0; i < 7; ++i) {
        s16x8 pb = *(const s16x8*)&Pm[i * 16 + l15][ks * 32 + quad * 8];
        a0[i] = __builtin_amdgcn_mfma_f32_16x16x32_bf16(va0, pb, a0[i], 0, 0, 0);
        a1[i] = __builtin_amdgcn_mfma_f32_16x16x32_bf16(va1, pb, a1[i], 0, 0, 0);
      }
      va0 = nva0; va1 = nva1;
    }

    // ---- epilogue: lane holds d = w*32 + quad*8 + {0..7} for n = nbase+i*16+l15 ----
#pragma unroll
    for (int i = 0; i < 7; ++i) {
      const int n = nbase + i * 16 + l15;
      if (n < 196) {
        const float is = inv_s[i * 16 + l15];
        s16x8 o;
        o[0] = (short)f2b(a0[i][0] * is); o[1] = (short)f2b(a0[i][1] * is);
        o[2] = (short)f2b(a0[i][2] * is); o[3] = (short)f2b(a0[i][3] * is);
        o[4] = (short)f2b(a1[i][0] * is); o[5] = (short)f2b(a1[i][1] * is);
        o[6] = (short)f2b(a1[i][2] * is); o[7] = (short)f2b(a1[i][3] * is);
        *(s16x8*)(ctxp + (size_t)n * CTX_ST + w * 32 + quad * 8) = o;
      }
    }
  }
}

extern "C" void kernel_launch(void* const* d_in, const int* in_sizes, int n_in,
                              void* d_out, int out_size, void* d_ws, size_t ws_size,
                              hipStream_t stream) {
  const float* x     = (const float*)d_in[0];
  const float* Wqkv  = (const float*)d_in[1];
  const float* bqkv  = (const float*)d_in[2];
  const float* Wproj = (const float*)d_in[3];
  const float* bproj = (const float*)d_in[4];
  const float* ab    = (const float*)d_in[5];
  float* out = (float*)d_out;

  const size_t szWq = 589824, szWp = 393216, szX = (size_t)B_SZ * N_TOKENS * DIM;
  const size_t fixedB = (szWq + szWp + szX) * 2;
  // per-batch: vt 8*128*208 + qkv 196*1536 + ctx 196*1024 elements (bf16)
  const size_t perB = (212992ULL + 301056ULL + 200704ULL) * 2;
  int Bs = 256;
  while (Bs > 32 && fixedB + (size_t)Bs * perB > ws_size) Bs >>= 1;

  unsigned short* Wqb  = (unsigned short*)d_ws;
  unsigned short* Wpb  = Wqb + szWq;
  unsigned short* xb   = Wpb + szWp;
  unsigned short* vtb  = xb + szX;
  unsigned short* qkvb = vtb + (size_t)Bs * 212992;
  unsigned short* ctxb = qkvb + (size_t)Bs * 301056;

  cvt_f32_bf16<<<dim3(576), dim3(256), 0, stream>>>(Wqkv, Wqb, (int)(szWq / 4));
  cvt_f32_bf16<<<dim3(384), dim3(256), 0, stream>>>(Wproj, Wpb, (int)(szWp / 4));
  cvt_f32_bf16<<<dim3(4096), dim3(256), 0, stream>>>(x, xb, (int)(szX / 4));
  {
    const int total = Bs * 8 * 128 * 12;
    zero_vt_pad<<<dim3((total + 255) / 256), dim3(256), 0, stream>>>(vtb, total);
  }

  const int nslice = B_SZ / Bs;
  const int Ms = Bs * N_TOKENS;
  for (int s = 0; s < nslice; ++s) {
    const unsigned short* xs = xb + (size_t)s * Ms * DIM;
    float* outs = out + (size_t)s * Ms * DIM;
    gemm_bf16_bt<1><<<dim3((Ms / 128) * (HID / 128)), dim3(256), 0, stream>>>(
        xs, Wqb, bqkv, qkvb, vtb, Ms, HID, DIM);
    attn_mfma<<<dim3(Bs * 8), dim3(256), 0, stream>>>(qkvb, vtb, ab, ctxb);
    gemm_bf16_bt<0><<<dim3((Ms / 128) * (DIM / 128)), dim3(256), 0, stream>>>(
        ctxb, Wpb, bproj, outs, nullptr, Ms, DIM, CTX_ST);
  }
}

// Round 7
// 495.523 us; speedup vs baseline: 1.9327x; 1.0616x over previous
//
#include <hip/hip_runtime.h>
#include <math.h>

#define B_SZ 256
#define N_TOKENS 196
#define DIM 384
#define NH 8
#define QKV_ST 1536      // NH*(2*32+128)
#define HID 1536
#define CTX_ST 1024      // NH*128
#define VT_ST 208        // padded token stride of V^T (13*16)

typedef short s16x8_base __attribute__((ext_vector_type(8)));
typedef s16x8_base __attribute__((may_alias)) s16x8;
typedef float f32x4_base __attribute__((ext_vector_type(4)));
typedef f32x4_base __attribute__((may_alias)) f32x4;

__device__ inline unsigned short f2b(float f) {
  union { float f; unsigned int u; } v; v.f = f;
  unsigned int r = (v.u + 0x7FFFu + ((v.u >> 16) & 1u)) >> 16;   // RNE, finite inputs
  return (unsigned short)r;
}

// ---------------- fp32 -> bf16 convert (vectorized, grid-stride) ----------------
__global__ __launch_bounds__(256)
void cvt_f32_bf16(const float* __restrict__ in, unsigned short* __restrict__ out, int n4) {
  int i = blockIdx.x * 256 + threadIdx.x;
  const int stride = gridDim.x * 256;
  for (; i < n4; i += stride) {
    float4 v = ((const float4*)in)[i];
    ushort4 o;
    o.x = f2b(v.x); o.y = f2b(v.y); o.z = f2b(v.z); o.w = f2b(v.w);
    ((ushort4*)out)[i] = o;
  }
}

// ---------------- zero V^T pad columns (tokens 196..207), once ----------------
__global__ __launch_bounds__(256)
void zero_vt_pad(unsigned short* __restrict__ vt, int total) {
  int i = blockIdx.x * 256 + threadIdx.x;    // over nbh*128*12
  if (i < total) {
    const int c = i % 12, rr = i / 12;       // rr = bh*128 + d
    vt[(size_t)rr * VT_ST + 196 + c] = 0;
  }
}

// ---------------- bf16 MFMA GEMM: C[M][N] = A[M][K] @ B[N][K]^T + bias ----------------
// (byte-identical to R6 — kept frozen this round for attribution)
// 128x128 tile, BK=32, 256 threads, wave-tile 64x64 (4x4 of 16x16x32).
// Reg-staged double-buffer prefetch. Operands swapped (acc = C^T frags): lane
// owns 4 consecutive C-cols -> packed stores.
// MODE 0: f32 out + bias (proj). MODE 1: qkv out — Q/K cols packed bf16 to C;
// V cols written TRANSPOSED to vt (fused transpose).
template <int MODE>
__global__ __launch_bounds__(256)
void gemm_bf16_bt(const unsigned short* __restrict__ A,
                  const unsigned short* __restrict__ Bm,
                  const float* __restrict__ bias,
                  void* __restrict__ C, unsigned short* __restrict__ vt,
                  int M, int N, int K) {
  __shared__ unsigned short As[128][32];
  __shared__ unsigned short Bs[128][32];
  const int tid = threadIdx.x;
  const int lane = tid & 63, wave = tid >> 6;
  const int quad = lane >> 4, l15 = lane & 15;
  const int ntile = N >> 7;
  const int bx = blockIdx.x % ntile, by = blockIdx.x / ntile;
  const int row0 = by << 7, col0 = bx << 7;

  const int srow = tid >> 1, soff = (tid & 1) << 4;   // staging: 32B per thread
  const unsigned short* Ag = A + (size_t)(row0 + srow) * K + soff;
  const unsigned short* Bg = Bm + (size_t)(col0 + srow) * K + soff;

  const int wr = (wave >> 1) << 6, wc = (wave & 1) << 6;

  f32x4 zero = {0.f, 0.f, 0.f, 0.f};
  f32x4 acc[4][4];
#pragma unroll
  for (int i = 0; i < 4; ++i)
#pragma unroll
    for (int j = 0; j < 4; ++j) acc[i][j] = zero;

  s16x8 a0 = *(const s16x8*)(Ag + 0);
  s16x8 a1 = *(const s16x8*)(Ag + 8);
  s16x8 b0 = *(const s16x8*)(Bg + 0);
  s16x8 b1 = *(const s16x8*)(Bg + 8);

  for (int k0 = 0; k0 < K; k0 += 32) {
    __syncthreads();
    *(s16x8*)&As[srow][soff] = a0;
    *(s16x8*)&As[srow][soff + 8] = a1;
    *(s16x8*)&Bs[srow][soff] = b0;
    *(s16x8*)&Bs[srow][soff + 8] = b1;
    __syncthreads();
    if (k0 + 32 < K) {
      a0 = *(const s16x8*)(Ag + k0 + 32);
      a1 = *(const s16x8*)(Ag + k0 + 40);
      b0 = *(const s16x8*)(Bg + k0 + 32);
      b1 = *(const s16x8*)(Bg + k0 + 40);
    }
    s16x8 af[4], bf[4];
#pragma unroll
    for (int i = 0; i < 4; ++i) {
      af[i] = *(const s16x8*)&As[wr + i * 16 + l15][quad * 8];
      bf[i] = *(const s16x8*)&Bs[wc + i * 16 + l15][quad * 8];
    }
#pragma unroll
    for (int i = 0; i < 4; ++i)
#pragma unroll
      for (int j = 0; j < 4; ++j)
        acc[i][j] = __builtin_amdgcn_mfma_f32_16x16x32_bf16(bf[j], af[i], acc[i][j], 0, 0, 0);
  }

  // epilogue: acc[i][j]: C-row = wr+i*16+l15, C-cols = wc+j*16+quad*4 + {0..3}
#pragma unroll
  for (int j = 0; j < 4; ++j) {
    const int colb = col0 + wc + j * 16 + quad * 4;
    const f32x4 bj = *(const f32x4*)&bias[colb];
    if (MODE == 0) {
#pragma unroll
      for (int i = 0; i < 4; ++i) {
        const int row = row0 + wr + i * 16 + l15;
        f32x4 v = acc[i][j] + bj;
        *(f32x4*)((float*)C + (size_t)row * N + colb) = v;
      }
    } else {
      const int hh = colb / 192;
      const int c192 = colb - hh * 192;
      if (c192 < 64) {
        // Q/K columns: packed bf16 into qkv
#pragma unroll
        for (int i = 0; i < 4; ++i) {
          const int row = row0 + wr + i * 16 + l15;
          f32x4 v = acc[i][j] + bj;
          ushort4 o;
          o.x = f2b(v[0]); o.y = f2b(v[1]); o.z = f2b(v[2]); o.w = f2b(v[3]);
          *(ushort4*)((unsigned short*)C + (size_t)row * N + colb) = o;
        }
      } else {
        // V columns: transposed into vt[bh*128+d][n]  (lanes -> contiguous n)
        const int d = c192 - 64;
#pragma unroll
        for (int i = 0; i < 4; ++i) {
          const int row = row0 + wr + i * 16 + l15;
          const int bl = row / 196;
          const int n = row - bl * 196;
          f32x4 v = acc[i][j] + bj;
          unsigned short* vp = vt + ((size_t)((bl * 8 + hh) * 128 + d)) * VT_ST + n;
#pragma unroll
          for (int r = 0; r < 4; ++r) vp[(size_t)r * VT_ST] = f2b(v[r]);
        }
      }
    }
  }
}

// ---------------- MFMA attention: one block per (b,h,chunk) ----------------
// Chunk split across BLOCKS (was: 2x112-row chunks looped inside one block).
// Grid = bh*4: chunks 0..2 = 64 rows (NT=4 tiles, 1 per wave, balanced),
// chunk 3 = rows 192..207 (NT=1, 4 valid rows). Finer blocks fix the tail
// (1024 blocks @3/CU -> 4096 @4/CU) that held avg occupancy at 10.6%.
// Inner math identical to R6: arithmetic bias, PV transposed from global
// (permuted d-rows), packed 16B ctx stores. LDS 30.7KB, VGPR<=128.
template <int NT>
__device__ __forceinline__ void attn_chunk64(
    const int nbase, const unsigned short* __restrict__ qbase,
    const unsigned short* __restrict__ vgw,
    const float* __restrict__ ab_s, unsigned short* __restrict__ ctxp,
    unsigned short (*__restrict__ Pm)[232], float* __restrict__ inv_s,
    const int w, const int quad, const int l15) {
  const float scale = 0.17677669529663687f;
  f32x4 zero = {0.f, 0.f, 0.f, 0.f};

  // ---- S phase: wave w owns tile row [nbase + w*16, +16) ----
  if (w < NT) {
    const int rowt = w * 16;
    s16x8 aq = *(const s16x8*)(qbase + (size_t)(nbase + rowt + l15) * QKV_ST + quad * 8);
    f32x4 sacc[13];
#pragma unroll
    for (int j = 0; j < 13; ++j) {
      s16x8 bk = *(const s16x8*)(qbase + (size_t)(j * 16 + l15) * QKV_ST + 32 + quad * 8);
      sacc[j] = __builtin_amdgcn_mfma_f32_16x16x32_bf16(aq, bk, zero, 0, 0, 0);
    }
    int rn4[4], cn4[4];
#pragma unroll
    for (int r = 0; r < 4; ++r) {
      const int n = nbase + rowt + quad * 4 + r;
      const int nn = n < 196 ? n : 195;
      rn4[r] = nn / 14;
      cn4[r] = nn - rn4[r] * 14;
    }
    float mx[4] = {-1e30f, -1e30f, -1e30f, -1e30f};
#pragma unroll
    for (int j = 0; j < 13; ++j) {
      const int m = j * 16 + l15;
      const int mc = m < 196 ? m : 195;
      const int rm = mc / 14, cm = mc - rm * 14;
#pragma unroll
      for (int r = 0; r < 4; ++r) {
        int dr = rn4[r] - rm; dr = dr < 0 ? -dr : dr;
        int dc = cn4[r] - cm; dc = dc < 0 ? -dc : dc;
        float s = fmaf(sacc[j][r], scale, ab_s[dr * 14 + dc]);
        s = (m < 196) ? s : -1e30f;    // unconditional overwrite: kills garbage-K NaN
        sacc[j][r] = s;
        mx[r] = fmaxf(mx[r], s);
      }
    }
#pragma unroll
    for (int o = 8; o > 0; o >>= 1)
#pragma unroll
      for (int r = 0; r < 4; ++r) mx[r] = fmaxf(mx[r], __shfl_xor(mx[r], o));
    float sm[4] = {0.f, 0.f, 0.f, 0.f};
#pragma unroll
    for (int j = 0; j < 13; ++j)
#pragma unroll
      for (int r = 0; r < 4; ++r) {
        float e = __expf(sacc[j][r] - mx[r]);
        sm[r] += e;
        Pm[rowt + quad * 4 + r][j * 16 + l15] = f2b(e);
      }
#pragma unroll
    for (int o = 8; o > 0; o >>= 1)
#pragma unroll
      for (int r = 0; r < 4; ++r) sm[r] += __shfl_xor(sm[r], o);
    if (l15 == 0) {
#pragma unroll
      for (int r = 0; r < 4; ++r) inv_s[rowt + quad * 4 + r] = 1.f / sm[r];
    }
  }
  __syncthreads();   // Pm + inv_s ready

  // ---- PV (transposed, barrier-free): wave owns d in [w*32, w*32+32) ----
  f32x4 a0[NT], a1[NT];
#pragma unroll
  for (int i = 0; i < NT; ++i) { a0[i] = zero; a1[i] = zero; }
  s16x8 va0 = *(const s16x8*)(vgw + 0);            // rows w*32 + pr
  s16x8 va1 = *(const s16x8*)(vgw + 4 * VT_ST);    // rows w*32 + pr + 4
#pragma unroll
  for (int ks = 0; ks < 7; ++ks) {
    s16x8 nva0, nva1;
    if (ks < 6) {
      nva0 = *(const s16x8*)(vgw + (ks + 1) * 32);
      nva1 = *(const s16x8*)(vgw + 4 * VT_ST + (ks + 1) * 32);
    }
#pragma unroll
    for (int i = 0; i < NT; ++i) {
      s16x8 pb = *(const s16x8*)&Pm[i * 16 + l15][ks * 32 + quad * 8];
      a0[i] = __builtin_amdgcn_mfma_f32_16x16x32_bf16(va0, pb, a0[i], 0, 0, 0);
      a1[i] = __builtin_amdgcn_mfma_f32_16x16x32_bf16(va1, pb, a1[i], 0, 0, 0);
    }
    va0 = nva0; va1 = nva1;
  }

  // ---- epilogue: lane holds d = w*32 + quad*8 + {0..7} for n = nbase+i*16+l15 ----
#pragma unroll
  for (int i = 0; i < NT; ++i) {
    const int n = nbase + i * 16 + l15;
    if (n < 196) {
      const float is = inv_s[i * 16 + l15];
      s16x8 o;
      o[0] = (short)f2b(a0[i][0] * is); o[1] = (short)f2b(a0[i][1] * is);
      o[2] = (short)f2b(a0[i][2] * is); o[3] = (short)f2b(a0[i][3] * is);
      o[4] = (short)f2b(a1[i][0] * is); o[5] = (short)f2b(a1[i][1] * is);
      o[6] = (short)f2b(a1[i][2] * is); o[7] = (short)f2b(a1[i][3] * is);
      *(s16x8*)(ctxp + (size_t)n * CTX_ST + w * 32 + quad * 8) = o;
    }
  }
}

__global__ __launch_bounds__(256, 4)
void attn_mfma(const unsigned short* __restrict__ qkv,
               const unsigned short* __restrict__ vt,
               const float* __restrict__ ab,
               unsigned short* __restrict__ ctx) {
  __shared__ unsigned short Pm[64][232];   // cols 208..231 zeroed (m-pad)
  __shared__ float inv_s[64];
  __shared__ float ab_s[196];

  const int bhc = blockIdx.x;
  const int bh = bhc >> 2, chunk = bhc & 3;
  const int b = bh >> 3, h = bh & 7;
  const int tid = threadIdx.x;
  const int lane = tid & 63, w = tid >> 6;
  const int quad = lane >> 4, l15 = lane & 15;

  const unsigned short* qbase = qkv + (size_t)b * N_TOKENS * QKV_ST + h * 192;
  // permuted A-row: lane l15 loads physical d-row perm(l15) = (l15&3) + (l15>>2)*8
  const int pr = (l15 & 3) + ((l15 >> 2) << 3);
  const unsigned short* vgw = vt + ((size_t)bh * 128 + w * 32 + pr) * VT_ST + quad * 8;
  unsigned short* ctxp = ctx + (size_t)b * N_TOKENS * CTX_ST + h * 128;

  if (tid < 196) ab_s[tid] = ab[h * 196 + tid];
  if (tid < 64) {
#pragma unroll
    for (int c = 208; c < 232; ++c) Pm[tid][c] = 0;   // zero m-pad: pad cols contribute 0
  }
  __syncthreads();   // ab_s + Pm pad visible

  if (chunk < 3)
    attn_chunk64<4>(chunk * 64, qbase, vgw, ab_s, ctxp, Pm, inv_s, w, quad, l15);
  else
    attn_chunk64<1>(192, qbase, vgw, ab_s, ctxp, Pm, inv_s, w, quad, l15);
}

extern "C" void kernel_launch(void* const* d_in, const int* in_sizes, int n_in,
                              void* d_out, int out_size, void* d_ws, size_t ws_size,
                              hipStream_t stream) {
  const float* x     = (const float*)d_in[0];
  const float* Wqkv  = (const float*)d_in[1];
  const float* bqkv  = (const float*)d_in[2];
  const float* Wproj = (const float*)d_in[3];
  const float* bproj = (const float*)d_in[4];
  const float* ab    = (const float*)d_in[5];
  float* out = (float*)d_out;

  const size_t szWq = 589824, szWp = 393216, szX = (size_t)B_SZ * N_TOKENS * DIM;
  const size_t QPAD = 12 * QKV_ST;                     // tail-chunk Q overread pad
  const size_t fixedB = (szWq + szWp + szX + QPAD) * 2;
  // per-batch: vt 8*128*208 + qkv 196*1536 + ctx 196*1024 elements (bf16)
  const size_t perB = (212992ULL + 301056ULL + 200704ULL) * 2;
  int Bs = 256;
  while (Bs > 32 && fixedB + (size_t)Bs * perB > ws_size) Bs >>= 1;

  unsigned short* Wqb  = (unsigned short*)d_ws;
  unsigned short* Wpb  = Wqb + szWq;
  unsigned short* xb   = Wpb + szWp;
  unsigned short* vtb  = xb + szX;
  unsigned short* qkvb = vtb + (size_t)Bs * 212992;
  unsigned short* ctxb = qkvb + (size_t)Bs * 301056 + QPAD;

  cvt_f32_bf16<<<dim3(576), dim3(256), 0, stream>>>(Wqkv, Wqb, (int)(szWq / 4));
  cvt_f32_bf16<<<dim3(384), dim3(256), 0, stream>>>(Wproj, Wpb, (int)(szWp / 4));
  cvt_f32_bf16<<<dim3(4096), dim3(256), 0, stream>>>(x, xb, (int)(szX / 4));
  {
    const int total = Bs * 8 * 128 * 12;
    zero_vt_pad<<<dim3((total + 255) / 256), dim3(256), 0, stream>>>(vtb, total);
  }

  const int nslice = B_SZ / Bs;
  const int Ms = Bs * N_TOKENS;
  for (int s = 0; s < nslice; ++s) {
    const unsigned short* xs = xb + (size_t)s * Ms * DIM;
    float* outs = out + (size_t)s * Ms * DIM;
    gemm_bf16_bt<1><<<dim3((Ms / 128) * (HID / 128)), dim3(256), 0, stream>>>(
        xs, Wqb, bqkv, qkvb, vtb, Ms, HID, DIM);
    attn_mfma<<<dim3(Bs * 8 * 4), dim3(256), 0, stream>>>(qkvb, vtb, ab, ctxb);
    gemm_bf16_bt<0><<<dim3((Ms / 128) * (DIM / 128)), dim3(256), 0, stream>>>(
        ctxb, Wpb, bproj, outs, nullptr, Ms, DIM, CTX_ST);
  }
}

// Round 8
// 446.511 us; speedup vs baseline: 2.1448x; 1.1098x over previous
//
#include <hip/hip_runtime.h>
#include <math.h>

#define B_SZ 256
#define N_TOKENS 196
#define DIM 384
#define NH 8
#define QKV_ST 1536      // NH*(2*32+128)
#define HID 1536
#define CTX_ST 1024      // NH*128
#define VT_ST 208        // padded token stride of V^T (13*16)

typedef short s16x8_base __attribute__((ext_vector_type(8)));
typedef s16x8_base __attribute__((may_alias)) s16x8;
typedef float f32x4_base __attribute__((ext_vector_type(4)));
typedef f32x4_base __attribute__((may_alias)) f32x4;

__device__ inline unsigned short f2b(float f) {
  union { float f; unsigned int u; } v; v.f = f;
  unsigned int r = (v.u + 0x7FFFu + ((v.u >> 16) & 1u)) >> 16;   // RNE, finite inputs
  return (unsigned short)r;
}

// Bijective XCD-chunked swizzle (m204): HW blockIdx round-robins the 8 XCDs;
// this remap gives each XCD a CONTIGUOUS work range -> shared tiles stay in
// that XCD's private L2.
__device__ inline int xcd_swizzle(int bid, int nwg) {
  const int q = nwg >> 3, r = nwg & 7;
  const int x = bid & 7, i = bid >> 3;
  return (x < r ? x * (q + 1) : r * (q + 1) + (x - r) * q) + i;
}

// ---------------- fp32 -> bf16 convert (vectorized, grid-stride) ----------------
__global__ __launch_bounds__(256)
void cvt_f32_bf16(const float* __restrict__ in, unsigned short* __restrict__ out, int n4) {
  int i = blockIdx.x * 256 + threadIdx.x;
  const int stride = gridDim.x * 256;
  for (; i < n4; i += stride) {
    float4 v = ((const float4*)in)[i];
    ushort4 o;
    o.x = f2b(v.x); o.y = f2b(v.y); o.z = f2b(v.z); o.w = f2b(v.w);
    ((ushort4*)out)[i] = o;
  }
}

// ---------------- zero V^T pad columns (tokens 196..207), once ----------------
__global__ __launch_bounds__(256)
void zero_vt_pad(unsigned short* __restrict__ vt, int total) {
  int i = blockIdx.x * 256 + threadIdx.x;    // over nbh*128*12
  if (i < total) {
    const int c = i % 12, rr = i / 12;       // rr = bh*128 + d
    vt[(size_t)rr * VT_ST + 196 + c] = 0;
  }
}

// ---------------- bf16 MFMA GEMM: C[M][N] = A[M][K] @ B[N][K]^T + bias ----------------
// 128x128 tile, BK=32, 256 threads, wave-tile 64x64 (4x4 of 16x16x32).
// NEW: single-barrier double-buffered LDS (ping-pong). Per K-step:
//   ds_write buf[t&1] -> issue next-tile global loads -> ONE barrier -> ds_read+MFMA.
// Correct because a wave's iter-t reads are lgkmcnt-drained before it enters
// barrier t+1, which orders them against the buf overwrite at iter t+2.
// Operands swapped (acc = C^T frags): lane owns 4 consecutive C-cols.
// MODE 0: f32 out + bias (proj). MODE 1: qkv out — Q/K packed bf16; V cols
// written TRANSPOSED to vt (fused transpose).
template <int MODE>
__global__ __launch_bounds__(256)
void gemm_bf16_bt(const unsigned short* __restrict__ A,
                  const unsigned short* __restrict__ Bm,
                  const float* __restrict__ bias,
                  void* __restrict__ C, unsigned short* __restrict__ vt,
                  int M, int N, int K) {
  __shared__ unsigned short As[2][128][32];
  __shared__ unsigned short Bs[2][128][32];
  const int tid = threadIdx.x;
  const int lane = tid & 63, wave = tid >> 6;
  const int quad = lane >> 4, l15 = lane & 15;
  const int ntile = N >> 7;
  const int wg = xcd_swizzle(blockIdx.x, gridDim.x);
  const int bx = wg % ntile, by = wg / ntile;
  const int row0 = by << 7, col0 = bx << 7;

  const int srow = tid >> 1, soff = (tid & 1) << 4;   // staging: 32B per thread
  const unsigned short* Ag = A + (size_t)(row0 + srow) * K + soff;
  const unsigned short* Bg = Bm + (size_t)(col0 + srow) * K + soff;

  const int wr = (wave >> 1) << 6, wc = (wave & 1) << 6;

  f32x4 zero = {0.f, 0.f, 0.f, 0.f};
  f32x4 acc[4][4];
#pragma unroll
  for (int i = 0; i < 4; ++i)
#pragma unroll
    for (int j = 0; j < 4; ++j) acc[i][j] = zero;

  s16x8 a0 = *(const s16x8*)(Ag + 0);
  s16x8 a1 = *(const s16x8*)(Ag + 8);
  s16x8 b0 = *(const s16x8*)(Bg + 0);
  s16x8 b1 = *(const s16x8*)(Bg + 8);

  const int nt = K >> 5;
#pragma unroll 1
  for (int t = 0; t < nt; ++t) {
    const int buf = t & 1;
    *(s16x8*)&As[buf][srow][soff] = a0;
    *(s16x8*)&As[buf][srow][soff + 8] = a1;
    *(s16x8*)&Bs[buf][srow][soff] = b0;
    *(s16x8*)&Bs[buf][srow][soff + 8] = b1;
    if (t + 1 < nt) {                         // issue early: covers barrier+reads+MFMA
      const int k1 = (t + 1) << 5;
      a0 = *(const s16x8*)(Ag + k1);
      a1 = *(const s16x8*)(Ag + k1 + 8);
      b0 = *(const s16x8*)(Bg + k1);
      b1 = *(const s16x8*)(Bg + k1 + 8);
    }
    __syncthreads();                          // buf ready for all waves
    s16x8 af[4], bf[4];
#pragma unroll
    for (int i = 0; i < 4; ++i) {
      af[i] = *(const s16x8*)&As[buf][wr + i * 16 + l15][quad * 8];
      bf[i] = *(const s16x8*)&Bs[buf][wc + i * 16 + l15][quad * 8];
    }
#pragma unroll
    for (int i = 0; i < 4; ++i)
#pragma unroll
      for (int j = 0; j < 4; ++j)
        acc[i][j] = __builtin_amdgcn_mfma_f32_16x16x32_bf16(bf[j], af[i], acc[i][j], 0, 0, 0);
  }

  // epilogue: acc[i][j]: C-row = wr+i*16+l15, C-cols = wc+j*16+quad*4 + {0..3}
#pragma unroll
  for (int j = 0; j < 4; ++j) {
    const int colb = col0 + wc + j * 16 + quad * 4;
    const f32x4 bj = *(const f32x4*)&bias[colb];
    if (MODE == 0) {
#pragma unroll
      for (int i = 0; i < 4; ++i) {
        const int row = row0 + wr + i * 16 + l15;
        f32x4 v = acc[i][j] + bj;
        *(f32x4*)((float*)C + (size_t)row * N + colb) = v;
      }
    } else {
      const int hh = colb / 192;
      const int c192 = colb - hh * 192;
      if (c192 < 64) {
        // Q/K columns: packed bf16 into qkv
#pragma unroll
        for (int i = 0; i < 4; ++i) {
          const int row = row0 + wr + i * 16 + l15;
          f32x4 v = acc[i][j] + bj;
          ushort4 o;
          o.x = f2b(v[0]); o.y = f2b(v[1]); o.z = f2b(v[2]); o.w = f2b(v[3]);
          *(ushort4*)((unsigned short*)C + (size_t)row * N + colb) = o;
        }
      } else {
        // V columns: transposed into vt[bh*128+d][n]  (lanes -> contiguous n)
        const int d = c192 - 64;
#pragma unroll
        for (int i = 0; i < 4; ++i) {
          const int row = row0 + wr + i * 16 + l15;
          const int bl = row / 196;
          const int n = row - bl * 196;
          f32x4 v = acc[i][j] + bj;
          unsigned short* vp = vt + ((size_t)((bl * 8 + hh) * 128 + d)) * VT_ST + n;
#pragma unroll
          for (int r = 0; r < 4; ++r) vp[(size_t)r * VT_ST] = f2b(v[r]);
        }
      }
    }
  }
}

// ---------------- MFMA attention: one block per (b,h,chunk) ----------------
// Grid = bh*4 (64-row chunks; chunk 3 = 4-row tail). XCD swizzle keeps the 4
// chunks of one bh on the same XCD -> K/V^T shared in its L2 (R7 showed the
// round-robin placement re-fetched them 4x: FETCH 173MB).
// Inner math identical to R7: arithmetic bias, PV transposed from global
// (permuted d-rows), packed 16B ctx stores. LDS 30.7KB, VGPR<=128.
template <int NT>
__device__ __forceinline__ void attn_chunk64(
    const int nbase, const unsigned short* __restrict__ qbase,
    const unsigned short* __restrict__ vgw,
    const float* __restrict__ ab_s, unsigned short* __restrict__ ctxp,
    unsigned short (*__restrict__ Pm)[232], float* __restrict__ inv_s,
    const int w, const int quad, const int l15) {
  const float scale = 0.17677669529663687f;
  f32x4 zero = {0.f, 0.f, 0.f, 0.f};

  // ---- S phase: wave w owns tile row [nbase + w*16, +16) ----
  if (w < NT) {
    const int rowt = w * 16;
    s16x8 aq = *(const s16x8*)(qbase + (size_t)(nbase + rowt + l15) * QKV_ST + quad * 8);
    f32x4 sacc[13];
#pragma unroll
    for (int j = 0; j < 13; ++j) {
      s16x8 bk = *(const s16x8*)(qbase + (size_t)(j * 16 + l15) * QKV_ST + 32 + quad * 8);
      sacc[j] = __builtin_amdgcn_mfma_f32_16x16x32_bf16(aq, bk, zero, 0, 0, 0);
    }
    int rn4[4], cn4[4];
#pragma unroll
    for (int r = 0; r < 4; ++r) {
      const int n = nbase + rowt + quad * 4 + r;
      const int nn = n < 196 ? n : 195;
      rn4[r] = nn / 14;
      cn4[r] = nn - rn4[r] * 14;
    }
    float mx[4] = {-1e30f, -1e30f, -1e30f, -1e30f};
#pragma unroll
    for (int j = 0; j < 13; ++j) {
      const int m = j * 16 + l15;
      const int mc = m < 196 ? m : 195;
      const int rm = mc / 14, cm = mc - rm * 14;
#pragma unroll
      for (int r = 0; r < 4; ++r) {
        int dr = rn4[r] - rm; dr = dr < 0 ? -dr : dr;
        int dc = cn4[r] - cm; dc = dc < 0 ? -dc : dc;
        float s = fmaf(sacc[j][r], scale, ab_s[dr * 14 + dc]);
        s = (m < 196) ? s : -1e30f;    // unconditional overwrite: kills garbage-K NaN
        sacc[j][r] = s;
        mx[r] = fmaxf(mx[r], s);
      }
    }
#pragma unroll
    for (int o = 8; o > 0; o >>= 1)
#pragma unroll
      for (int r = 0; r < 4; ++r) mx[r] = fmaxf(mx[r], __shfl_xor(mx[r], o));
    float sm[4] = {0.f, 0.f, 0.f, 0.f};
#pragma unroll
    for (int j = 0; j < 13; ++j)
#pragma unroll
      for (int r = 0; r < 4; ++r) {
        float e = __expf(sacc[j][r] - mx[r]);
        sm[r] += e;
        Pm[rowt + quad * 4 + r][j * 16 + l15] = f2b(e);
      }
#pragma unroll
    for (int o = 8; o > 0; o >>= 1)
#pragma unroll
      for (int r = 0; r < 4; ++r) sm[r] += __shfl_xor(sm[r], o);
    if (l15 == 0) {
#pragma unroll
      for (int r = 0; r < 4; ++r) inv_s[rowt + quad * 4 + r] = 1.f / sm[r];
    }
  }
  __syncthreads();   // Pm + inv_s ready

  // ---- PV (transposed, barrier-free): wave owns d in [w*32, w*32+32) ----
  f32x4 a0[NT], a1[NT];
#pragma unroll
  for (int i = 0; i < NT; ++i) { a0[i] = zero; a1[i] = zero; }
  s16x8 va0 = *(const s16x8*)(vgw + 0);            // rows w*32 + pr
  s16x8 va1 = *(const s16x8*)(vgw + 4 * VT_ST);    // rows w*32 + pr + 4
#pragma unroll
  for (int ks = 0; ks < 7; ++ks) {
    s16x8 nva0, nva1;
    if (ks < 6) {
      nva0 = *(const s16x8*)(vgw + (ks + 1) * 32);
      nva1 = *(const s16x8*)(vgw + 4 * VT_ST + (ks + 1) * 32);
    }
#pragma unroll
    for (int i = 0; i < NT; ++i) {
      s16x8 pb = *(const s16x8*)&Pm[i * 16 + l15][ks * 32 + quad * 8];
      a0[i] = __builtin_amdgcn_mfma_f32_16x16x32_bf16(va0, pb, a0[i], 0, 0, 0);
      a1[i] = __builtin_amdgcn_mfma_f32_16x16x32_bf16(va1, pb, a1[i], 0, 0, 0);
    }
    va0 = nva0; va1 = nva1;
  }

  // ---- epilogue: lane holds d = w*32 + quad*8 + {0..7} for n = nbase+i*16+l15 ----
#pragma unroll
  for (int i = 0; i < NT; ++i) {
    const int n = nbase + i * 16 + l15;
    if (n < 196) {
      const float is = inv_s[i * 16 + l15];
      s16x8 o;
      o[0] = (short)f2b(a0[i][0] * is); o[1] = (short)f2b(a0[i][1] * is);
      o[2] = (short)f2b(a0[i][2] * is); o[3] = (short)f2b(a0[i][3] * is);
      o[4] = (short)f2b(a1[i][0] * is); o[5] = (short)f2b(a1[i][1] * is);
      o[6] = (short)f2b(a1[i][2] * is); o[7] = (short)f2b(a1[i][3] * is);
      *(s16x8*)(ctxp + (size_t)n * CTX_ST + w * 32 + quad * 8) = o;
    }
  }
}

__global__ __launch_bounds__(256, 4)
void attn_mfma(const unsigned short* __restrict__ qkv,
               const unsigned short* __restrict__ vt,
               const float* __restrict__ ab,
               unsigned short* __restrict__ ctx) {
  __shared__ unsigned short Pm[64][232];   // cols 208..231 zeroed (m-pad)
  __shared__ float inv_s[64];
  __shared__ float ab_s[196];

  const int bhc = xcd_swizzle(blockIdx.x, gridDim.x);
  const int bh = bhc >> 2, chunk = bhc & 3;
  const int b = bh >> 3, h = bh & 7;
  const int tid = threadIdx.x;
  const int lane = tid & 63, w = tid >> 6;
  const int quad = lane >> 4, l15 = lane & 15;

  const unsigned short* qbase = qkv + (size_t)b * N_TOKENS * QKV_ST + h * 192;
  // permuted A-row: lane l15 loads physical d-row perm(l15) = (l15&3) + (l15>>2)*8
  const int pr = (l15 & 3) + ((l15 >> 2) << 3);
  const unsigned short* vgw = vt + ((size_t)bh * 128 + w * 32 + pr) * VT_ST + quad * 8;
  unsigned short* ctxp = ctx + (size_t)b * N_TOKENS * CTX_ST + h * 128;

  if (tid < 196) ab_s[tid] = ab[h * 196 + tid];
  if (tid < 64) {
#pragma unroll
    for (int c = 208; c < 232; ++c) Pm[tid][c] = 0;   // zero m-pad: pad cols contribute 0
  }
  __syncthreads();   // ab_s + Pm pad visible

  if (chunk < 3)
    attn_chunk64<4>(chunk * 64, qbase, vgw, ab_s, ctxp, Pm, inv_s, w, quad, l15);
  else
    attn_chunk64<1>(192, qbase, vgw, ab_s, ctxp, Pm, inv_s, w, quad, l15);
}

extern "C" void kernel_launch(void* const* d_in, const int* in_sizes, int n_in,
                              void* d_out, int out_size, void* d_ws, size_t ws_size,
                              hipStream_t stream) {
  const float* x     = (const float*)d_in[0];
  const float* Wqkv  = (const float*)d_in[1];
  const float* bqkv  = (const float*)d_in[2];
  const float* Wproj = (const float*)d_in[3];
  const float* bproj = (const float*)d_in[4];
  const float* ab    = (const float*)d_in[5];
  float* out = (float*)d_out;

  const size_t szWq = 589824, szWp = 393216, szX = (size_t)B_SZ * N_TOKENS * DIM;
  const size_t QPAD = 12 * QKV_ST;                     // tail-chunk Q overread pad
  const size_t fixedB = (szWq + szWp + szX + QPAD) * 2;
  // per-batch: vt 8*128*208 + qkv 196*1536 + ctx 196*1024 elements (bf16)
  const size_t perB = (212992ULL + 301056ULL + 200704ULL) * 2;
  int Bs = 256;
  while (Bs > 32 && fixedB + (size_t)Bs * perB > ws_size) Bs >>= 1;

  unsigned short* Wqb  = (unsigned short*)d_ws;
  unsigned short* Wpb  = Wqb + szWq;
  unsigned short* xb   = Wpb + szWp;
  unsigned short* vtb  = xb + szX;
  unsigned short* qkvb = vtb + (size_t)Bs * 212992;
  unsigned short* ctxb = qkvb + (size_t)Bs * 301056 + QPAD;

  cvt_f32_bf16<<<dim3(576), dim3(256), 0, stream>>>(Wqkv, Wqb, (int)(szWq / 4));
  cvt_f32_bf16<<<dim3(384), dim3(256), 0, stream>>>(Wproj, Wpb, (int)(szWp / 4));
  cvt_f32_bf16<<<dim3(4096), dim3(256), 0, stream>>>(x, xb, (int)(szX / 4));
  {
    const int total = Bs * 8 * 128 * 12;
    zero_vt_pad<<<dim3((total + 255) / 256), dim3(256), 0, stream>>>(vtb, total);
  }

  const int nslice = B_SZ / Bs;
  const int Ms = Bs * N_TOKENS;
  for (int s = 0; s < nslice; ++s) {
    const unsigned short* xs = xb + (size_t)s * Ms * DIM;
    float* outs = out + (size_t)s * Ms * DIM;
    gemm_bf16_bt<1><<<dim3((Ms / 128) * (HID / 128)), dim3(256), 0, stream>>>(
        xs, Wqb, bqkv, qkvb, vtb, Ms, HID, DIM);
    attn_mfma<<<dim3(Bs * 8 * 4), dim3(256), 0, stream>>>(qkvb, vtb, ab, ctxb);
    gemm_bf16_bt<0><<<dim3((Ms / 128) * (DIM / 128)), dim3(256), 0, stream>>>(
        ctxb, Wpb, bproj, outs, nullptr, Ms, DIM, CTX_ST);
  }
}

// Round 9
// 439.872 us; speedup vs baseline: 2.1772x; 1.0151x over previous
//
#include <hip/hip_runtime.h>
#include <math.h>

#define B_SZ 256
#define N_TOKENS 196
#define DIM 384
#define NH 8
#define QK_ST 512        // compact Q/K buffer stride: h*64 + {0..31 q, 32..63 k}
#define HID 1536
#define CTX_ST 1024      // NH*128
#define VT_ST 208        // padded token stride of V^T (13*16)
#define LP 40            // padded LDS row stride (elements): 80B -> conflict-free reads

typedef short s16x8_base __attribute__((ext_vector_type(8)));
typedef s16x8_base __attribute__((may_alias)) s16x8;
typedef float f32x4_base __attribute__((ext_vector_type(4)));
typedef f32x4_base __attribute__((may_alias)) f32x4;

__device__ inline unsigned short f2b(float f) {
  union { float f; unsigned int u; } v; v.f = f;
  unsigned int r = (v.u + 0x7FFFu + ((v.u >> 16) & 1u)) >> 16;   // RNE, finite inputs
  return (unsigned short)r;
}

// Bijective XCD-chunked swizzle (m204): contiguous work range per XCD.
__device__ inline int xcd_swizzle(int bid, int nwg) {
  const int q = nwg >> 3, r = nwg & 7;
  const int x = bid & 7, i = bid >> 3;
  return (x < r ? x * (q + 1) : r * (q + 1) + (x - r) * q) + i;
}

// ---------------- fp32 -> bf16 convert (vectorized, grid-stride) ----------------
__global__ __launch_bounds__(256)
void cvt_f32_bf16(const float* __restrict__ in, unsigned short* __restrict__ out, int n4) {
  int i = blockIdx.x * 256 + threadIdx.x;
  const int stride = gridDim.x * 256;
  for (; i < n4; i += stride) {
    float4 v = ((const float4*)in)[i];
    ushort4 o;
    o.x = f2b(v.x); o.y = f2b(v.y); o.z = f2b(v.z); o.w = f2b(v.w);
    ((ushort4*)out)[i] = o;
  }
}

// ---------------- zero V^T pad columns (tokens 196..207), once ----------------
__global__ __launch_bounds__(256)
void zero_vt_pad(unsigned short* __restrict__ vt, int total) {
  int i = blockIdx.x * 256 + threadIdx.x;    // over nbh*128*12
  if (i < total) {
    const int c = i % 12, rr = i / 12;       // rr = bh*128 + d
    vt[(size_t)rr * VT_ST + 196 + c] = 0;
  }
}

// ---------------- bf16 MFMA GEMM: C[M][N] = A[M][K] @ B[N][K]^T + bias ----------------
// 128x128 tile, BK=32, 256 threads, wave-tile 64x64 (4x4 of 16x16x32).
// Single-barrier double-buffered LDS (R8) + PADDED stride 40 (80B): fragment
// reads go from 8-way bank conflict (64B stride: banks (16r+4q)%32) to 2-way
// free (banks (20r+4q)%32 span 8 slots). R8 PMC: 7.2M SQ_LDS_BANK_CONFLICT.
// Operands swapped (acc = C^T frags): lane owns 4 consecutive C-cols.
// MODE 0: f32 out + bias (proj). MODE 1: Q/K cols packed bf16 into compact
// qk buffer (stride 512); V cols TRANSPOSED to vt (fused transpose).
template <int MODE>
__global__ __launch_bounds__(256)
void gemm_bf16_bt(const unsigned short* __restrict__ A,
                  const unsigned short* __restrict__ Bm,
                  const float* __restrict__ bias,
                  void* __restrict__ C, unsigned short* __restrict__ vt,
                  int M, int N, int K) {
  __shared__ unsigned short As[2][128][LP];
  __shared__ unsigned short Bs[2][128][LP];
  const int tid = threadIdx.x;
  const int lane = tid & 63, wave = tid >> 6;
  const int quad = lane >> 4, l15 = lane & 15;
  const int ntile = N >> 7;
  const int wg = xcd_swizzle(blockIdx.x, gridDim.x);
  const int bx = wg % ntile, by = wg / ntile;
  const int row0 = by << 7, col0 = bx << 7;

  const int srow = tid >> 1, soff = (tid & 1) << 4;   // staging: 32B per thread
  const unsigned short* Ag = A + (size_t)(row0 + srow) * K + soff;
  const unsigned short* Bg = Bm + (size_t)(col0 + srow) * K + soff;

  const int wr = (wave >> 1) << 6, wc = (wave & 1) << 6;

  f32x4 zero = {0.f, 0.f, 0.f, 0.f};
  f32x4 acc[4][4];
#pragma unroll
  for (int i = 0; i < 4; ++i)
#pragma unroll
    for (int j = 0; j < 4; ++j) acc[i][j] = zero;

  s16x8 a0 = *(const s16x8*)(Ag + 0);
  s16x8 a1 = *(const s16x8*)(Ag + 8);
  s16x8 b0 = *(const s16x8*)(Bg + 0);
  s16x8 b1 = *(const s16x8*)(Bg + 8);

  const int nt = K >> 5;
#pragma unroll 1
  for (int t = 0; t < nt; ++t) {
    const int buf = t & 1;
    *(s16x8*)&As[buf][srow][soff] = a0;
    *(s16x8*)&As[buf][srow][soff + 8] = a1;
    *(s16x8*)&Bs[buf][srow][soff] = b0;
    *(s16x8*)&Bs[buf][srow][soff + 8] = b1;
    if (t + 1 < nt) {                         // issue early: covers barrier+reads+MFMA
      const int k1 = (t + 1) << 5;
      a0 = *(const s16x8*)(Ag + k1);
      a1 = *(const s16x8*)(Ag + k1 + 8);
      b0 = *(const s16x8*)(Bg + k1);
      b1 = *(const s16x8*)(Bg + k1 + 8);
    }
    __syncthreads();                          // buf ready for all waves
    s16x8 af[4], bf[4];
#pragma unroll
    for (int i = 0; i < 4; ++i) {
      af[i] = *(const s16x8*)&As[buf][wr + i * 16 + l15][quad * 8];
      bf[i] = *(const s16x8*)&Bs[buf][wc + i * 16 + l15][quad * 8];
    }
#pragma unroll
    for (int i = 0; i < 4; ++i)
#pragma unroll
      for (int j = 0; j < 4; ++j)
        acc[i][j] = __builtin_amdgcn_mfma_f32_16x16x32_bf16(bf[j], af[i], acc[i][j], 0, 0, 0);
  }

  // epilogue: acc[i][j]: C-row = wr+i*16+l15, C-cols = wc+j*16+quad*4 + {0..3}
#pragma unroll
  for (int j = 0; j < 4; ++j) {
    const int colb = col0 + wc + j * 16 + quad * 4;
    const f32x4 bj = *(const f32x4*)&bias[colb];
    if (MODE == 0) {
#pragma unroll
      for (int i = 0; i < 4; ++i) {
        const int row = row0 + wr + i * 16 + l15;
        f32x4 v = acc[i][j] + bj;
        *(f32x4*)((float*)C + (size_t)row * N + colb) = v;
      }
    } else {
      const int hh = colb / 192;
      const int c192 = colb - hh * 192;
      if (c192 < 64) {
        // Q/K columns: packed bf16 into compact qk buffer (stride 512)
#pragma unroll
        for (int i = 0; i < 4; ++i) {
          const int row = row0 + wr + i * 16 + l15;
          f32x4 v = acc[i][j] + bj;
          ushort4 o;
          o.x = f2b(v[0]); o.y = f2b(v[1]); o.z = f2b(v[2]); o.w = f2b(v[3]);
          *(ushort4*)((unsigned short*)C + (size_t)row * QK_ST + hh * 64 + c192) = o;
        }
      } else {
        // V columns: transposed into vt[bh*128+d][n]  (lanes -> contiguous n)
        const int d = c192 - 64;
#pragma unroll
        for (int i = 0; i < 4; ++i) {
          const int row = row0 + wr + i * 16 + l15;
          const int bl = row / 196;
          const int n = row - bl * 196;
          f32x4 v = acc[i][j] + bj;
          unsigned short* vp = vt + ((size_t)((bl * 8 + hh) * 128 + d)) * VT_ST + n;
#pragma unroll
          for (int r = 0; r < 4; ++r) vp[(size_t)r * VT_ST] = f2b(v[r]);
        }
      }
    }
  }
}

// ---------------- MFMA attention: one block per (b,h,chunk) ----------------
// Grid = bh*4 (64-row chunks; chunk 3 = 4-row tail), XCD swizzle (R8).
// Q/K from compact qk buffer (stride 512). Arithmetic bias, PV transposed
// from global (permuted d-rows), packed 16B ctx stores. LDS 30.7KB.
template <int NT>
__device__ __forceinline__ void attn_chunk64(
    const int nbase, const unsigned short* __restrict__ qbase,
    const unsigned short* __restrict__ vgw,
    const float* __restrict__ ab_s, unsigned short* __restrict__ ctxp,
    unsigned short (*__restrict__ Pm)[232], float* __restrict__ inv_s,
    const int w, const int quad, const int l15) {
  const float scale = 0.17677669529663687f;
  f32x4 zero = {0.f, 0.f, 0.f, 0.f};

  // ---- S phase: wave w owns tile row [nbase + w*16, +16) ----
  if (w < NT) {
    const int rowt = w * 16;
    s16x8 aq = *(const s16x8*)(qbase + (size_t)(nbase + rowt + l15) * QK_ST + quad * 8);
    f32x4 sacc[13];
#pragma unroll
    for (int j = 0; j < 13; ++j) {
      s16x8 bk = *(const s16x8*)(qbase + (size_t)(j * 16 + l15) * QK_ST + 32 + quad * 8);
      sacc[j] = __builtin_amdgcn_mfma_f32_16x16x32_bf16(aq, bk, zero, 0, 0, 0);
    }
    int rn4[4], cn4[4];
#pragma unroll
    for (int r = 0; r < 4; ++r) {
      const int n = nbase + rowt + quad * 4 + r;
      const int nn = n < 196 ? n : 195;
      rn4[r] = nn / 14;
      cn4[r] = nn - rn4[r] * 14;
    }
    float mx[4] = {-1e30f, -1e30f, -1e30f, -1e30f};
#pragma unroll
    for (int j = 0; j < 13; ++j) {
      const int m = j * 16 + l15;
      const int mc = m < 196 ? m : 195;
      const int rm = mc / 14, cm = mc - rm * 14;
#pragma unroll
      for (int r = 0; r < 4; ++r) {
        int dr = rn4[r] - rm; dr = dr < 0 ? -dr : dr;
        int dc = cn4[r] - cm; dc = dc < 0 ? -dc : dc;
        float s = fmaf(sacc[j][r], scale, ab_s[dr * 14 + dc]);
        s = (m < 196) ? s : -1e30f;    // unconditional overwrite: kills garbage-K NaN
        sacc[j][r] = s;
        mx[r] = fmaxf(mx[r], s);
      }
    }
#pragma unroll
    for (int o = 8; o > 0; o >>= 1)
#pragma unroll
      for (int r = 0; r < 4; ++r) mx[r] = fmaxf(mx[r], __shfl_xor(mx[r], o));
    float sm[4] = {0.f, 0.f, 0.f, 0.f};
#pragma unroll
    for (int j = 0; j < 13; ++j)
#pragma unroll
      for (int r = 0; r < 4; ++r) {
        float e = __expf(sacc[j][r] - mx[r]);
        sm[r] += e;
        Pm[rowt + quad * 4 + r][j * 16 + l15] = f2b(e);
      }
#pragma unroll
    for (int o = 8; o > 0; o >>= 1)
#pragma unroll
      for (int r = 0; r < 4; ++r) sm[r] += __shfl_xor(sm[r], o);
    if (l15 == 0) {
#pragma unroll
      for (int r = 0; r < 4; ++r) inv_s[rowt + quad * 4 + r] = 1.f / sm[r];
    }
  }
  __syncthreads();   // Pm + inv_s ready

  // ---- PV (transposed, barrier-free): wave owns d in [w*32, w*32+32) ----
  f32x4 a0[NT], a1[NT];
#pragma unroll
  for (int i = 0; i < NT; ++i) { a0[i] = zero; a1[i] = zero; }
  s16x8 va0 = *(const s16x8*)(vgw + 0);            // rows w*32 + pr
  s16x8 va1 = *(const s16x8*)(vgw + 4 * VT_ST);    // rows w*32 + pr + 4
#pragma unroll
  for (int ks = 0; ks < 7; ++ks) {
    s16x8 nva0, nva1;
    if (ks < 6) {
      nva0 = *(const s16x8*)(vgw + (ks + 1) * 32);
      nva1 = *(const s16x8*)(vgw + 4 * VT_ST + (ks + 1) * 32);
    }
#pragma unroll
    for (int i = 0; i < NT; ++i) {
      s16x8 pb = *(const s16x8*)&Pm[i * 16 + l15][ks * 32 + quad * 8];
      a0[i] = __builtin_amdgcn_mfma_f32_16x16x32_bf16(va0, pb, a0[i], 0, 0, 0);
      a1[i] = __builtin_amdgcn_mfma_f32_16x16x32_bf16(va1, pb, a1[i], 0, 0, 0);
    }
    va0 = nva0; va1 = nva1;
  }

  // ---- epilogue: lane holds d = w*32 + quad*8 + {0..7} for n = nbase+i*16+l15 ----
#pragma unroll
  for (int i = 0; i < NT; ++i) {
    const int n = nbase + i * 16 + l15;
    if (n < 196) {
      const float is = inv_s[i * 16 + l15];
      s16x8 o;
      o[0] = (short)f2b(a0[i][0] * is); o[1] = (short)f2b(a0[i][1] * is);
      o[2] = (short)f2b(a0[i][2] * is); o[3] = (short)f2b(a0[i][3] * is);
      o[4] = (short)f2b(a1[i][0] * is); o[5] = (short)f2b(a1[i][1] * is);
      o[6] = (short)f2b(a1[i][2] * is); o[7] = (short)f2b(a1[i][3] * is);
      *(s16x8*)(ctxp + (size_t)n * CTX_ST + w * 32 + quad * 8) = o;
    }
  }
}

__global__ __launch_bounds__(256, 4)
void attn_mfma(const unsigned short* __restrict__ qk,
               const unsigned short* __restrict__ vt,
               const float* __restrict__ ab,
               unsigned short* __restrict__ ctx) {
  __shared__ unsigned short Pm[64][232];   // cols 208..231 zeroed (m-pad)
  __shared__ float inv_s[64];
  __shared__ float ab_s[196];

  const int bhc = xcd_swizzle(blockIdx.x, gridDim.x);
  const int bh = bhc >> 2, chunk = bhc & 3;
  const int b = bh >> 3, h = bh & 7;
  const int tid = threadIdx.x;
  const int lane = tid & 63, w = tid >> 6;
  const int quad = lane >> 4, l15 = lane & 15;

  const unsigned short* qbase = qk + (size_t)b * N_TOKENS * QK_ST + h * 64;
  // permuted A-row: lane l15 loads physical d-row perm(l15) = (l15&3) + (l15>>2)*8
  const int pr = (l15 & 3) + ((l15 >> 2) << 3);
  const unsigned short* vgw = vt + ((size_t)bh * 128 + w * 32 + pr) * VT_ST + quad * 8;
  unsigned short* ctxp = ctx + (size_t)b * N_TOKENS * CTX_ST + h * 128;

  if (tid < 196) ab_s[tid] = ab[h * 196 + tid];
  if (tid < 64) {
#pragma unroll
    for (int c = 208; c < 232; ++c) Pm[tid][c] = 0;   // zero m-pad: pad cols contribute 0
  }
  __syncthreads();   // ab_s + Pm pad visible

  if (chunk < 3)
    attn_chunk64<4>(chunk * 64, qbase, vgw, ab_s, ctxp, Pm, inv_s, w, quad, l15);
  else
    attn_chunk64<1>(192, qbase, vgw, ab_s, ctxp, Pm, inv_s, w, quad, l15);
}

extern "C" void kernel_launch(void* const* d_in, const int* in_sizes, int n_in,
                              void* d_out, int out_size, void* d_ws, size_t ws_size,
                              hipStream_t stream) {
  const float* x     = (const float*)d_in[0];
  const float* Wqkv  = (const float*)d_in[1];
  const float* bqkv  = (const float*)d_in[2];
  const float* Wproj = (const float*)d_in[3];
  const float* bproj = (const float*)d_in[4];
  const float* ab    = (const float*)d_in[5];
  float* out = (float*)d_out;

  const size_t szWq = 589824, szWp = 393216, szX = (size_t)B_SZ * N_TOKENS * DIM;
  const size_t QPAD = 12 * QK_ST;                      // tail-chunk Q overread pad
  const size_t fixedB = (szWq + szWp + szX + QPAD) * 2;
  // per-batch: vt 8*128*208 + qk 196*512 + ctx 196*1024 elements (bf16)
  const size_t perB = (212992ULL + 100352ULL + 200704ULL) * 2;
  int Bs = 256;
  while (Bs > 32 && fixedB + (size_t)Bs * perB > ws_size) Bs >>= 1;

  unsigned short* Wqb  = (unsigned short*)d_ws;
  unsigned short* Wpb  = Wqb + szWq;
  unsigned short* xb   = Wpb + szWp;
  unsigned short* vtb  = xb + szX;
  unsigned short* qkb  = vtb + (size_t)Bs * 212992;
  unsigned short* ctxb = qkb + (size_t)Bs * 100352 + QPAD;

  cvt_f32_bf16<<<dim3(576), dim3(256), 0, stream>>>(Wqkv, Wqb, (int)(szWq / 4));
  cvt_f32_bf16<<<dim3(384), dim3(256), 0, stream>>>(Wproj, Wpb, (int)(szWp / 4));
  cvt_f32_bf16<<<dim3(4096), dim3(256), 0, stream>>>(x, xb, (int)(szX / 4));
  {
    const int total = Bs * 8 * 128 * 12;
    zero_vt_pad<<<dim3((total + 255) / 256), dim3(256), 0, stream>>>(vtb, total);
  }

  const int nslice = B_SZ / Bs;
  const int Ms = Bs * N_TOKENS;
  for (int s = 0; s < nslice; ++s) {
    const unsigned short* xs = xb + (size_t)s * Ms * DIM;
    float* outs = out + (size_t)s * Ms * DIM;
    gemm_bf16_bt<1><<<dim3((Ms / 128) * (HID / 128)), dim3(256), 0, stream>>>(
        xs, Wqb, bqkv, qkb, vtb, Ms, HID, DIM);
    attn_mfma<<<dim3(Bs * 8 * 4), dim3(256), 0, stream>>>(qkb, vtb, ab, ctxb);
    gemm_bf16_bt<0><<<dim3((Ms / 128) * (DIM / 128)), dim3(256), 0, stream>>>(
        ctxb, Wpb, bproj, outs, nullptr, Ms, DIM, CTX_ST);
  }
}